// Round 9
// baseline (768.546 us; speedup 1.0000x reference)
//
#include <hip/hip_runtime.h>
#include <math.h>

#define NN 20000
#define NP 20480   // padded to 160*128 (full supertile groups)
#define EE 60000
#define BB 512
#define HC 1024
#define HH 4
#define CC 256

typedef _Float16 f16;
typedef f16 half8 __attribute__((ext_vector_type(8)));
typedef f16 f16x4 __attribute__((ext_vector_type(4)));
typedef float floatx4 __attribute__((ext_vector_type(4)));
typedef float floatx16 __attribute__((ext_vector_type(16)));

__device__ __forceinline__ void load_lds16(const void* g, void* l) {
    __builtin_amdgcn_global_load_lds((const __attribute__((address_space(1))) void*)g,
                                     (__attribute__((address_space(3))) void*)l, 16, 0, 0);
}

// ---------------- precompute kernels ----------------
__global__ void ea_sum_kernel(const float* __restrict__ ea, float* sums, int E_) {
    float s0 = 0.f, s1 = 0.f, s2 = 0.f;
    for (int e = blockIdx.x * 256 + threadIdx.x; e < E_; e += gridDim.x * 256) {
        s0 += ea[e * 3 + 0];
        s1 += ea[e * 3 + 1];
        s2 += ea[e * 3 + 2];
    }
    for (int o = 32; o; o >>= 1) {
        s0 += __shfl_down(s0, o);
        s1 += __shfl_down(s1, o);
        s2 += __shfl_down(s2, o);
    }
    if ((threadIdx.x & 63) == 0) {
        atomicAdd(&sums[0], s0);
        atomicAdd(&sums[1], s1);
        atomicAdd(&sums[2], s2);
    }
}

__global__ void hist_kernel(const int* __restrict__ ei, int* counts, int E_) {
    int e = blockIdx.x * 256 + threadIdx.x;
    if (e < E_) atomicAdd(&counts[ei[E_ + e]], 1);
}

// two-level scan
__global__ void scan1_kernel(const int* __restrict__ counts, int* __restrict__ partial,
                             int* __restrict__ psums, int n) {
    __shared__ int sdata[256];
    int t = threadIdx.x;
    int i = blockIdx.x * 256 + t;
    int v = (i < n) ? counts[i] : 0;
    sdata[t] = v;
    __syncthreads();
#pragma unroll
    for (int off = 1; off < 256; off <<= 1) {
        int tmp = (t >= off) ? sdata[t - off] : 0;
        __syncthreads();
        sdata[t] += tmp;
        __syncthreads();
    }
    if (i < n) partial[i] = sdata[t];
    if (t == 255) psums[blockIdx.x] = sdata[255];
}

__global__ void scan2_kernel(int* __restrict__ psums, int nb) {
    __shared__ int sdata[128];
    int t = threadIdx.x;
    sdata[t] = (t < nb) ? psums[t] : 0;
    __syncthreads();
#pragma unroll
    for (int off = 1; off < 128; off <<= 1) {
        int tmp = (t >= off) ? sdata[t - off] : 0;
        __syncthreads();
        sdata[t] += tmp;
        __syncthreads();
    }
    if (t < nb) psums[t] = (t == 0) ? 0 : sdata[t - 1];
}

__global__ void scan3_kernel(const int* __restrict__ partial, const int* __restrict__ psums,
                             int* __restrict__ indptr, int n) {
    int i = blockIdx.x * 256 + threadIdx.x;
    if (i == 0) indptr[0] = 0;
    if (i < n) indptr[i + 1] = partial[i] + psums[blockIdx.x];
}

__global__ void scatter_kernel(const int* __restrict__ ei, const int* __restrict__ indptr,
                               int* fill, int* sorted, int E_) {
    int e = blockIdx.x * 256 + threadIdx.x;
    if (e >= E_) return;
    int d = ei[E_ + e];
    int pos = indptr[d] + atomicAdd(&fill[d], 1);
    sorted[pos] = e;
}

__global__ void bptr_kernel(const int* __restrict__ batch, int* bptr, int n, int nb) {
    int i = blockIdx.x * 256 + threadIdx.x;
    if (i >= n) return;
    int b = batch[i];
    if (i == 0) {
        for (int bb = 0; bb <= b; bb++) bptr[bb] = 0;
    } else {
        int pb = batch[i - 1];
        if (pb != b) {
            for (int bb = pb + 1; bb <= b; bb++) bptr[bb] = i;
        }
    }
    if (i == n - 1) {
        for (int bb = b + 1; bb <= nb; bb++) bptr[bb] = n;
    }
}

// transpose+convert w_rest[3][1024][1024] fp32 -> wt[3][n][k] fp16 (B^T)
__global__ void wconv_kernel(const float* __restrict__ w_rest, f16* __restrict__ wt) {
    __shared__ float tile[64][65];
    int l = blockIdx.z;
    int bx = blockIdx.x * 64;
    int by = blockIdx.y * 64;
    int t = threadIdx.x;
    int tr = t >> 6, tc = t & 63;
#pragma unroll
    for (int i = 0; i < 16; i++) {
        int r = by + i * 4 + tr;
        tile[i * 4 + tr][tc] = w_rest[(size_t)l * 1048576 + (size_t)r * 1024 + bx + tc];
    }
    __syncthreads();
#pragma unroll
    for (int i = 0; i < 16; i++) {
        int n = bx + i * 4 + tr;
        wt[(size_t)l * 1048576 + (size_t)n * 1024 + by + tc] = (f16)tile[tc][i * 4 + tr];
    }
}

// Mmat[l][d][h]; ae_self[l][h]
__global__ void mmat_all_kernel(const float* __restrict__ w_edge,
                                const float* __restrict__ att_edge,
                                const float* __restrict__ ea_sums, float* Mmat,
                                float* ae_self, float invE) {
    __shared__ float red[256];
    __shared__ float Ms[12];
    int l = blockIdx.x;
    int t = threadIdx.x;
    for (int dh = 0; dh < 12; dh++) {
        int d = dh >> 2, hh = dh & 3;
        float v = w_edge[l * 3072 + d * HC + hh * CC + t] * att_edge[l * HC + hh * CC + t];
        red[t] = v;
        __syncthreads();
        for (int o = 128; o; o >>= 1) {
            if (t < o) red[t] += red[t + o];
            __syncthreads();
        }
        if (t == 0) {
            Ms[dh] = red[0];
            Mmat[l * 12 + dh] = red[0];
        }
        __syncthreads();
    }
    if (t < 4) {
        float v = 0.f;
        for (int d = 0; d < 3; d++) v += ea_sums[d] * invE * Ms[d * 4 + t];
        ae_self[l * 4 + t] = v;
    }
}

// pack CSR
__global__ void pack_kernel(const int* __restrict__ ei, const int* __restrict__ sorted,
                            const float* __restrict__ ea, const float* __restrict__ Mmat,
                            int* __restrict__ ssrc, float* __restrict__ aeh_pk) {
    int idx = blockIdx.x * 256 + threadIdx.x;
    if (idx >= EE) return;
    int eid = sorted[idx];
    ssrc[idx] = ei[eid];
    float a0 = ea[eid * 3 + 0], a1 = ea[eid * 3 + 1], a2 = ea[eid * 3 + 2];
#pragma unroll
    for (int l = 0; l < 4; l++) {
#pragma unroll
        for (int h = 0; h < 4; h++) {
            aeh_pk[(size_t)idx * 16 + l * 4 + h] =
                a0 * Mmat[l * 12 + h] + a1 * Mmat[l * 12 + 4 + h] + a2 * Mmat[l * 12 + 8 + h];
        }
    }
}

__global__ void edgep_kernel(const int* __restrict__ ssrc, const float* __restrict__ aeh_pk,
                             const float* __restrict__ asrc, float* __restrict__ q,
                             int layer) {
    int i = blockIdx.x * 256 + threadIdx.x;
    if (i >= EE) return;
    int src = ssrc[i];
    float4 a = *(const float4*)&asrc[(size_t)src * 4];
    float4 m = *(const float4*)&aeh_pk[(size_t)i * 16 + layer * 4];
    float4 o;
    o.x = a.x + m.x;
    o.y = a.y + m.y;
    o.z = a.z + m.z;
    o.w = a.w + m.w;
    *(float4*)&q[(size_t)i * 4] = o;
}

__global__ void bnss_kernel(const float* __restrict__ bias012, const float* __restrict__ bn_g,
                            const float* __restrict__ bn_b, const float* __restrict__ bn_m,
                            const float* __restrict__ bn_v, float2* __restrict__ bnss) {
    int i = blockIdx.x * 256 + threadIdx.x;
    if (i >= 3 * HC) return;
    float s = bn_g[i] * rsqrtf(bn_v[i] + 1e-5f);
    float2 o;
    o.x = s;
    o.y = (bias012[i] - bn_m[i]) * s + bn_b[i];
    bnss[i] = o;
}

__global__ void wvec_kernel(const float* __restrict__ w_rest, const float* __restrict__ att_src,
                            const float* __restrict__ att_dst, float* __restrict__ wsv,
                            float* __restrict__ wdv) {
    int l = blockIdx.y;
    int k = blockIdx.x;
    int t = threadIdx.x;
    int hp = t >> 6, lane = t & 63;
    int col = hp * 256 + lane * 4;
    const float* wrow = w_rest + (size_t)l * 1048576 + (size_t)k * 1024;
    float4 w4 = *(const float4*)&wrow[col];
    float4 a4 = *(const float4*)&att_src[(l + 1) * HC + col];
    float4 d4 = *(const float4*)&att_dst[(l + 1) * HC + col];
    float sp = w4.x * a4.x + w4.y * a4.y + w4.z * a4.z + w4.w * a4.w;
    float dp = w4.x * d4.x + w4.y * d4.y + w4.z * d4.z + w4.w * d4.w;
    for (int m = 1; m < 64; m <<= 1) {
        sp += __shfl_xor(sp, m);
        dp += __shfl_xor(dp, m);
    }
    if (lane == 0) {
        wsv[((size_t)l * 1024 + k) * 4 + hp] = sp;
        wdv[((size_t)l * 1024 + k) * 4 + hp] = dp;
    }
}

__global__ void w0vec_kernel(const float* __restrict__ w0, const float* __restrict__ att_src,
                             const float* __restrict__ att_dst, float* __restrict__ w0s,
                             float* __restrict__ w0d) {
    int f = blockIdx.x;
    int t = threadIdx.x;
    int hp = t >> 6, lane = t & 63;
    int col = hp * 256 + lane * 4;
    float4 w4 = *(const float4*)&w0[f * HC + col];
    float4 a4 = *(const float4*)&att_src[col];
    float4 d4 = *(const float4*)&att_dst[col];
    float sp = w4.x * a4.x + w4.y * a4.y + w4.z * a4.z + w4.w * a4.w;
    float dp = w4.x * d4.x + w4.y * d4.y + w4.z * d4.z + w4.w * d4.w;
    for (int m = 1; m < 64; m <<= 1) {
        sp += __shfl_xor(sp, m);
        dp += __shfl_xor(dp, m);
    }
    if (lane == 0) {
        w0s[f * 4 + hp] = sp;
        w0d[f * 4 + hp] = dp;
    }
}

__global__ void alpha0_kernel(const float* __restrict__ x, const float* __restrict__ w0s,
                              const float* __restrict__ w0d, float* __restrict__ asrc,
                              float* __restrict__ adst) {
    int n = blockIdx.x * 256 + threadIdx.x;
    if (n >= NN) return;
    float xr[7];
#pragma unroll
    for (int f = 0; f < 7; f++) xr[f] = x[n * 7 + f];
#pragma unroll
    for (int hp = 0; hp < 4; hp++) {
        float s = 0.f, d = 0.f;
#pragma unroll
        for (int f = 0; f < 7; f++) {
            s += xr[f] * w0s[f * 4 + hp];
            d += xr[f] * w0d[f * 4 + hp];
        }
        asrc[n * 4 + hp] = s;
        adst[n * 4 + hp] = d;
    }
}

// ---------------- layer 0 (commuted) ----------------
__global__ void agg0x_kernel(const float* __restrict__ x, const float* __restrict__ asrc,
                             const float* __restrict__ adst, const float* __restrict__ ae_self,
                             const int* __restrict__ ssrc, const float* __restrict__ q,
                             const int* __restrict__ indptr, float* __restrict__ xagg) {
    int n = blockIdx.x * 256 + threadIdx.x;
    if (n >= NN) return;
    float4 as4 = *(const float4*)&asrc[(size_t)n * 4];
    float4 ad4 = *(const float4*)&adst[(size_t)n * 4];
    float adl[4] = {ad4.x, ad4.y, ad4.z, ad4.w};
    float asl[4] = {as4.x, as4.y, as4.z, as4.w};
    float xr[7];
#pragma unroll
    for (int f = 0; f < 7; f++) xr[f] = x[n * 7 + f];
    float denom[4];
    float xa[4][7];
#pragma unroll
    for (int h = 0; h < 4; h++) {
        float r = asl[h] + adl[h] + ae_self[h];
        r = (r > 0.f) ? r : 0.2f * r;
        float p = __expf(r);
        denom[h] = p;
#pragma unroll
        for (int f = 0; f < 7; f++) xa[h][f] = p * xr[f];
    }
    int s = indptr[n], e = indptr[n + 1];
    for (int idx = s; idx < e; idx++) {
        int src = ssrc[idx];
        float4 qv = *(const float4*)&q[(size_t)idx * 4];
        float ql[4] = {qv.x, qv.y, qv.z, qv.w};
        float xs[7];
#pragma unroll
        for (int f = 0; f < 7; f++) xs[f] = x[src * 7 + f];
#pragma unroll
        for (int h = 0; h < 4; h++) {
            float rr = ql[h] + adl[h];
            rr = (rr > 0.f) ? rr : 0.2f * rr;
            float pe = __expf(rr);
            denom[h] += pe;
#pragma unroll
            for (int f = 0; f < 7; f++) xa[h][f] += pe * xs[f];
        }
    }
#pragma unroll
    for (int h = 0; h < 4; h++) {
        float inv = 1.0f / (denom[h] + 1e-16f);
#pragma unroll
        for (int f = 0; f < 7; f++) xagg[(size_t)n * 28 + h * 7 + f] = xa[h][f] * inv;
    }
}

__global__ void gemm7f_kernel(const float* __restrict__ xagg, const float* __restrict__ w0,
                              const float2* __restrict__ bnss, const float* __restrict__ wsv,
                              const float* __restrict__ wdv, f16* __restrict__ out16,
                              float* __restrict__ asrc_n, float* __restrict__ adst_n) {
    __shared__ float xs[28];
    __shared__ float red[32];
    int n = blockIdx.x, t = threadIdx.x;
    if (t < 28) xs[t] = xagg[(size_t)n * 28 + t];
    __syncthreads();
    float sp[4] = {0.f, 0.f, 0.f, 0.f}, dp[4] = {0.f, 0.f, 0.f, 0.f};
#pragma unroll
    for (int k = 0; k < 4; k++) {
        int j = k * 256 + t;
        float dot = 0.f;
#pragma unroll
        for (int f = 0; f < 7; f++) dot += xs[k * 7 + f] * w0[f * HC + j];
        float2 ss = bnss[j];
        float val = fmaxf(fmaf(dot, ss.x, ss.y), 0.f);
        out16[(size_t)n * HC + j] = (f16)val;
        float4 w4s = *(const float4*)&wsv[(size_t)j * 4];
        float4 w4d = *(const float4*)&wdv[(size_t)j * 4];
        sp[0] += val * w4s.x; sp[1] += val * w4s.y;
        sp[2] += val * w4s.z; sp[3] += val * w4s.w;
        dp[0] += val * w4d.x; dp[1] += val * w4d.y;
        dp[2] += val * w4d.z; dp[3] += val * w4d.w;
    }
    int wave = t >> 6, lane = t & 63;
#pragma unroll
    for (int m = 1; m < 64; m <<= 1) {
#pragma unroll
        for (int j = 0; j < 4; j++) {
            sp[j] += __shfl_xor(sp[j], m);
            dp[j] += __shfl_xor(dp[j], m);
        }
    }
    if (lane == 0) {
#pragma unroll
        for (int j = 0; j < 4; j++) {
            red[wave * 8 + j] = sp[j];
            red[wave * 8 + 4 + j] = dp[j];
        }
    }
    __syncthreads();
    if (t < 8) {
        float v = red[t] + red[8 + t] + red[16 + t] + red[24 + t];
        if (t < 4) asrc_n[n * 4 + t] = v;
        else adst_n[n * 4 + (t - 4)] = v;
    }
}

// ---------------- GEMM (layers 1-3) ----------------
// Double-buffered LDS: prefetch iter k+1 AFTER the barrier, compute iter k.
// The barrier's vmcnt(0) drain then has the whole compute phase of head start.
// 32x32x16 MFMA operand-swapped epilogue; L2 supertile 8m x 8n; M padded.
__global__ __launch_bounds__(256) void mfma_gemm_kernel(const f16* __restrict__ A,
                                                        const f16* __restrict__ Bt,
                                                        f16* __restrict__ C16,
                                                        int N, int K) {
    __shared__ f16 As[2][4 * 128 * 8];
    __shared__ f16 Bs[2][4 * 128 * 8];
    int t = threadIdx.x;
    int wave = t >> 6, lane = t & 63;
    int wr = (wave >> 1) * 64;
    int wc = (wave & 1) * 64;
    int gid = blockIdx.x;
    int g = gid >> 6;
    int rblk = gid & 63;
    int n0 = (rblk >> 3) * 128;
    int m0 = (g * 8 + (rblk & 7)) * 128;

    floatx16 acc[2][2];
#pragma unroll
    for (int i = 0; i < 2; i++)
#pragma unroll
        for (int j = 0; j < 2; j++) acc[i][j] = (floatx16)(0.f);

    int q0 = t >> 7, r0 = t & 127;
    int q1 = (256 + t) >> 7, r1 = (256 + t) & 127;
    const f16* pa0 = A + (size_t)(m0 + r0) * K + q0 * 8;
    const f16* pa1 = A + (size_t)(m0 + r1) * K + q1 * 8;
    const f16* pb0 = Bt + (size_t)(n0 + r0) * K + q0 * 8;
    const f16* pb1 = Bt + (size_t)(n0 + r1) * K + q1 * 8;
    int lo0 = t * 8, lo1 = (256 + t) * 8;

    int fr32 = lane & 31, kg = lane >> 5;

    // prologue: stage iter 0 into buf 0
    load_lds16(pa0, &As[0][lo0]);
    load_lds16(pa1, &As[0][lo1]);
    load_lds16(pb0, &Bs[0][lo0]);
    load_lds16(pb1, &Bs[0][lo1]);

    int cur = 0;
    for (int k0 = 0; k0 < K; k0 += 32) {
        __syncthreads();   // drains prefetch -> buf[cur] ready
        if (k0 + 32 < K) {
            int nxt = cur ^ 1;
            load_lds16(pa0 + k0 + 32, &As[nxt][lo0]);
            load_lds16(pa1 + k0 + 32, &As[nxt][lo1]);
            load_lds16(pb0 + k0 + 32, &Bs[nxt][lo0]);
            load_lds16(pb1 + k0 + 32, &Bs[nxt][lo1]);
        }
#pragma unroll
        for (int kh = 0; kh < 2; kh++) {
            half8 af[2], bf[2];
#pragma unroll
            for (int i = 0; i < 2; i++)
                af[i] = *(const half8*)&As[cur][((kh * 2 + kg) * 128 + wr + i * 32 + fr32) * 8];
#pragma unroll
            for (int j = 0; j < 2; j++)
                bf[j] = *(const half8*)&Bs[cur][((kh * 2 + kg) * 128 + wc + j * 32 + fr32) * 8];
#pragma unroll
            for (int i = 0; i < 2; i++)
#pragma unroll
                for (int j = 0; j < 2; j++)
                    acc[i][j] = __builtin_amdgcn_mfma_f32_32x32x16_f16(bf[j], af[i],
                                                                       acc[i][j], 0, 0, 0);
        }
        cur ^= 1;
    }

#pragma unroll
    for (int i = 0; i < 2; i++) {
        int row = m0 + wr + i * 32 + fr32;
#pragma unroll
        for (int j = 0; j < 2; j++) {
#pragma unroll
            for (int gq = 0; gq < 4; gq++) {
                f16x4 o;
#pragma unroll
                for (int r = 0; r < 4; r++) o[r] = (f16)acc[i][j][gq * 4 + r];
                *(f16x4*)&C16[(size_t)row * N + n0 + wc + j * 32 + gq * 8 + kg * 4] = o;
            }
        }
    }
}

// ---------------- fused attention + aggregation (block per node, chunk-4) ----------
__global__ void agg_kernel(const f16* __restrict__ h16, const float* __restrict__ asrc,
                           const float* __restrict__ adst, const float* __restrict__ ae_self,
                           const int* __restrict__ ssrc, const float* __restrict__ q,
                           const int* __restrict__ indptr, const float2* __restrict__ bnss,
                           const float* __restrict__ wsv, const float* __restrict__ wdv,
                           const float* __restrict__ bias3, f16* __restrict__ out16,
                           float* __restrict__ asrc_n, float* __restrict__ adst_n,
                           float* __restrict__ out3, int layer, int concat) {
    __shared__ float buf[1024];
    __shared__ float red[32];
    int n = blockIdx.x, t = threadIdx.x;
    int h = t >> 6, lane = t & 63;
    int c4 = t * 4;

    float adst_nh = adst[n * 4 + h];
    float r = asrc[n * 4 + h] + adst_nh + ae_self[layer * 4 + h];
    r = (r > 0.f) ? r : 0.2f * r;
    float p = __expf(r);
    float denom = p;
    float ax, ay, az, aw;
    {
        f16x4 v = *(const f16x4*)&h16[(size_t)n * HC + c4];
        ax = p * (float)v[0]; ay = p * (float)v[1];
        az = p * (float)v[2]; aw = p * (float)v[3];
    }
    int s = indptr[n], epos = indptr[n + 1];
    for (int base = s; base < epos; base += 4) {
        int rem = epos - base;
        int src[4];
        float qv[4];
#pragma unroll
        for (int j = 0; j < 4; j++) {
            if (j < rem) {
                src[j] = ssrc[base + j];
                qv[j] = q[(size_t)(base + j) * 4 + h];
            } else {
                src[j] = n;
                qv[j] = -1e9f;
            }
        }
        f16x4 u[4];
#pragma unroll
        for (int j = 0; j < 4; j++) u[j] = *(const f16x4*)&h16[(size_t)src[j] * HC + c4];
#pragma unroll
        for (int j = 0; j < 4; j++) {
            float rr = qv[j] + adst_nh;
            rr = (rr > 0.f) ? rr : 0.2f * rr;
            float pe = __expf(rr);
            denom += pe;
            ax += pe * (float)u[j][0];
            ay += pe * (float)u[j][1];
            az += pe * (float)u[j][2];
            aw += pe * (float)u[j][3];
        }
    }
    float inv = 1.0f / (denom + 1e-16f);
    ax *= inv; ay *= inv; az *= inv; aw *= inv;

    if (concat) {
        float vals[4] = {ax, ay, az, aw};
        f16x4 o;
        float sp[4] = {0.f, 0.f, 0.f, 0.f}, dp[4] = {0.f, 0.f, 0.f, 0.f};
#pragma unroll
        for (int k = 0; k < 4; k++) {
            int j = c4 + k;
            float2 ss = bnss[j];
            float val = fmaxf(fmaf(vals[k], ss.x, ss.y), 0.f);
            o[k] = (f16)val;
            float4 w4s = *(const float4*)&wsv[(size_t)j * 4];
            float4 w4d = *(const float4*)&wdv[(size_t)j * 4];
            sp[0] += val * w4s.x; sp[1] += val * w4s.y;
            sp[2] += val * w4s.z; sp[3] += val * w4s.w;
            dp[0] += val * w4d.x; dp[1] += val * w4d.y;
            dp[2] += val * w4d.z; dp[3] += val * w4d.w;
        }
        *(f16x4*)&out16[(size_t)n * HC + c4] = o;
#pragma unroll
        for (int m = 1; m < 64; m <<= 1) {
#pragma unroll
            for (int j = 0; j < 4; j++) {
                sp[j] += __shfl_xor(sp[j], m);
                dp[j] += __shfl_xor(dp[j], m);
            }
        }
        if (lane == 0) {
#pragma unroll
            for (int j = 0; j < 4; j++) {
                red[h * 8 + j] = sp[j];
                red[h * 8 + 4 + j] = dp[j];
            }
        }
        __syncthreads();
        if (t < 8) {
            float v = red[t] + red[8 + t] + red[16 + t] + red[24 + t];
            if (t < 4) asrc_n[n * 4 + t] = v;
            else adst_n[n * 4 + (t - 4)] = v;
        }
    } else {
        buf[c4 + 0] = ax;
        buf[c4 + 1] = ay;
        buf[c4 + 2] = az;
        buf[c4 + 3] = aw;
        __syncthreads();
        if (t < 64) {
#pragma unroll
            for (int k = 0; k < 4; k++) {
                int c = t * 4 + k;
                float v2 = 0.25f * (buf[c] + buf[256 + c] + buf[512 + c] + buf[768 + c]) +
                           bias3[c];
                out3[(size_t)n * CC + c] = v2;
            }
        }
    }
}

// ---------------- readout ----------------
__global__ void gate_kernel(const float* __restrict__ h3, const float* __restrict__ gw,
                            const float* __restrict__ gb, float* gate) {
    int node = blockIdx.x * 4 + (threadIdx.x >> 6);
    int lane = threadIdx.x & 63;
    if (node >= NN) return;
    const float4 hv = *(const float4*)&h3[(size_t)node * CC + lane * 4];
    const float4 w4 = *(const float4*)&gw[lane * 4];
    float s = hv.x * w4.x + hv.y * w4.y + hv.z * w4.z + hv.w * w4.w;
    for (int o = 32; o; o >>= 1) s += __shfl_down(s, o);
    if (lane == 0) gate[node] = s + gb[0];
}

__global__ void graphagg_kernel(const float* __restrict__ gate, const float* __restrict__ h3,
                                const int* __restrict__ bptr, float* __restrict__ graph) {
    __shared__ float red[256];
    __shared__ float wn[256];
    int b = blockIdx.x, t = threadIdx.x;
    int s = bptr[b], epos = bptr[b + 1];
    float m = -3.4e38f;
    for (int n = s + t; n < epos; n += 256) m = fmaxf(m, gate[n]);
    red[t] = m;
    __syncthreads();
    for (int o = 128; o; o >>= 1) {
        if (t < o) red[t] = fmaxf(red[t], red[t + o]);
        __syncthreads();
    }
    float mval = red[0];
    __syncthreads();
    float sum = 0.f;
    for (int n = s + t; n < epos; n += 256) sum += __expf(gate[n] - mval);
    red[t] = sum;
    __syncthreads();
    for (int o = 128; o; o >>= 1) {
        if (t < o) red[t] += red[t + o];
        __syncthreads();
    }
    float ssum = red[0];
    __syncthreads();
    float acc = 0.f;
    for (int base = s; base < epos; base += 256) {
        int n = base + t;
        wn[t] = (n < epos) ? __expf(gate[n] - mval) : 0.f;
        __syncthreads();
        int cnt = min(256, epos - base);
        for (int j = 0; j < cnt; j++) acc += wn[j] * h3[(size_t)(base + j) * CC + t];
        __syncthreads();
    }
    graph[b * CC + t] = acc / (ssum + 1e-16f);
}

// 8 graphs per block: proj_w L2 traffic 512MB -> 64MB
__global__ void proj_kernel(const float* __restrict__ graph, const float* __restrict__ pw,
                            const float* __restrict__ pb, float* __restrict__ out) {
    __shared__ float g[8][256];
    int b0 = blockIdx.x * 8, t = threadIdx.x;
#pragma unroll
    for (int i = 0; i < 8; i++) g[i][t] = graph[(size_t)(b0 + i) * CC + t];
    __syncthreads();
    for (int j = t; j < 1024; j += 256) {
        float a0, a1, a2, a3, a4, a5, a6, a7;
        float bj = pb[j];
        a0 = a1 = a2 = a3 = a4 = a5 = a6 = a7 = bj;
        for (int c = 0; c < 256; c++) {
            float w = pw[c * 1024 + j];
            a0 += g[0][c] * w; a1 += g[1][c] * w;
            a2 += g[2][c] * w; a3 += g[3][c] * w;
            a4 += g[4][c] * w; a5 += g[5][c] * w;
            a6 += g[6][c] * w; a7 += g[7][c] * w;
        }
        out[(size_t)(b0 + 0) * 1024 + j] = a0;
        out[(size_t)(b0 + 1) * 1024 + j] = a1;
        out[(size_t)(b0 + 2) * 1024 + j] = a2;
        out[(size_t)(b0 + 3) * 1024 + j] = a3;
        out[(size_t)(b0 + 4) * 1024 + j] = a4;
        out[(size_t)(b0 + 5) * 1024 + j] = a5;
        out[(size_t)(b0 + 6) * 1024 + j] = a6;
        out[(size_t)(b0 + 7) * 1024 + j] = a7;
    }
}

// ---------------- host ----------------
extern "C" void kernel_launch(void* const* d_in, const int* in_sizes, int n_in,
                              void* d_out, int out_size, void* d_ws, size_t ws_size,
                              hipStream_t stream) {
    const float* x = (const float*)d_in[0];
    const int* ei = (const int*)d_in[1];
    const float* ea = (const float*)d_in[2];
    const int* batch = (const int*)d_in[3];
    const float* w0 = (const float*)d_in[4];
    const float* w_rest = (const float*)d_in[5];
    const float* w_edge = (const float*)d_in[6];
    const float* att_src = (const float*)d_in[7];
    const float* att_dst = (const float*)d_in[8];
    const float* att_edge = (const float*)d_in[9];
    const float* bias012 = (const float*)d_in[10];
    const float* bias3 = (const float*)d_in[11];
    const float* bn_g = (const float*)d_in[12];
    const float* bn_b = (const float*)d_in[13];
    const float* bn_m = (const float*)d_in[14];
    const float* bn_v = (const float*)d_in[15];
    const float* gate_w = (const float*)d_in[16];
    const float* gate_b = (const float*)d_in[17];
    const float* proj_w = (const float*)d_in[18];
    const float* proj_b = (const float*)d_in[19];
    float* out = (float*)d_out;

    float* ws = (float*)d_ws;
    size_t off = 0;
    f16* h_lin = (f16*)(ws + off); off += (size_t)NP * HC / 2;
    f16* h_in = (f16*)(ws + off); off += (size_t)NP * HC / 2;
    float* h3 = ws + off; off += (size_t)NN * CC;
    f16* wt = (f16*)(ws + off); off += (size_t)3 * HC * HC / 2;
    float* asrcA = ws + off; off += (size_t)NN * 4;
    float* adstA = ws + off; off += (size_t)NN * 4;
    float* asrcB = ws + off; off += (size_t)NN * 4;
    float* adstB = ws + off; off += (size_t)NN * 4;
    float* wsv = ws + off; off += (size_t)3 * HC * 4;
    float* wdv = ws + off; off += (size_t)3 * HC * 4;
    float* w0s = ws + off; off += 28;
    float* w0d = ws + off; off += 28;
    float2* bnss = (float2*)(ws + off); off += (size_t)3 * HC * 2;
    float* aeh_pk = ws + off; off += (size_t)EE * 16;
    float* qbuf = ws + off; off += (size_t)EE * 4;
    float* xagg = ws + off; off += (size_t)NN * 28;
    float* gate = ws + off; off += (size_t)NN;
    float* graph = ws + off; off += (size_t)BB * CC;
    float* ea_sums = ws + off; off += 4;
    float* Mmat = ws + off; off += 48;
    float* ae_self = ws + off; off += 16;
    int* counts = (int*)(ws + off); off += NN;
    int* partial = (int*)(ws + off); off += NN;
    int* psums = (int*)(ws + off); off += 128;
    int* indptr = (int*)(ws + off); off += NN + 1;
    int* fill = (int*)(ws + off); off += NN;
    int* sorted = (int*)(ws + off); off += EE;
    int* ssrc = (int*)(ws + off); off += EE;
    int* bptr = (int*)(ws + off); off += BB + 1;

    hipMemsetAsync(ea_sums, 0, 4 * sizeof(float), stream);
    hipMemsetAsync(counts, 0, NN * sizeof(int), stream);
    hipMemsetAsync(fill, 0, NN * sizeof(int), stream);

    ea_sum_kernel<<<64, 256, 0, stream>>>(ea, ea_sums, EE);
    hist_kernel<<<(EE + 255) / 256, 256, 0, stream>>>(ei, counts, EE);
    int nblk = (NN + 255) / 256;  // 79
    scan1_kernel<<<nblk, 256, 0, stream>>>(counts, partial, psums, NN);
    scan2_kernel<<<1, 128, 0, stream>>>(psums, nblk);
    scan3_kernel<<<nblk, 256, 0, stream>>>(partial, psums, indptr, NN);
    scatter_kernel<<<(EE + 255) / 256, 256, 0, stream>>>(ei, indptr, fill, sorted, EE);
    bptr_kernel<<<(NN + 255) / 256, 256, 0, stream>>>(batch, bptr, NN, BB);
    wconv_kernel<<<dim3(16, 16, 3), 256, 0, stream>>>(w_rest, wt);
    mmat_all_kernel<<<4, 256, 0, stream>>>(w_edge, att_edge, ea_sums, Mmat, ae_self,
                                           1.0f / EE);
    pack_kernel<<<(EE + 255) / 256, 256, 0, stream>>>(ei, sorted, ea, Mmat, ssrc, aeh_pk);
    bnss_kernel<<<(3 * HC + 255) / 256, 256, 0, stream>>>(bias012, bn_g, bn_b, bn_m, bn_v,
                                                          bnss);
    wvec_kernel<<<dim3(1024, 3), 256, 0, stream>>>(w_rest, att_src, att_dst, wsv, wdv);
    w0vec_kernel<<<7, 256, 0, stream>>>(w0, att_src, att_dst, w0s, w0d);
    alpha0_kernel<<<(NN + 255) / 256, 256, 0, stream>>>(x, w0s, w0d, asrcA, adstA);

    // ---- layer 0 (commuted) ----
    edgep_kernel<<<(EE + 255) / 256, 256, 0, stream>>>(ssrc, aeh_pk, asrcA, qbuf, 0);
    agg0x_kernel<<<(NN + 255) / 256, 256, 0, stream>>>(x, asrcA, adstA, ae_self, ssrc,
                                                       qbuf, indptr, xagg);
    gemm7f_kernel<<<NN, 256, 0, stream>>>(xagg, w0, bnss, wsv, wdv, h_in, asrcB, adstB);

    float* asrc_cur = asrcB;
    float* adst_cur = adstB;
    float* asrc_nxt = asrcA;
    float* adst_nxt = adstA;
    for (int i = 1; i < 4; i++) {
        mfma_gemm_kernel<<<(NP / 128) * (HC / 128), 256, 0, stream>>>(
            h_in, wt + (size_t)(i - 1) * HC * HC, h_lin, HC, HC);
        edgep_kernel<<<(EE + 255) / 256, 256, 0, stream>>>(ssrc, aeh_pk, asrc_cur, qbuf, i);
        agg_kernel<<<NN, 256, 0, stream>>>(
            h_lin, asrc_cur, adst_cur, ae_self, ssrc, qbuf, indptr, bnss + (size_t)i * HC,
            wsv + (size_t)i * HC * 4, wdv + (size_t)i * HC * 4, bias3, h_in, asrc_nxt,
            adst_nxt, h3, i, (i < 3) ? 1 : 0);
        float* tmp = asrc_cur; asrc_cur = asrc_nxt; asrc_nxt = tmp;
        tmp = adst_cur; adst_cur = adst_nxt; adst_nxt = tmp;
    }

    gate_kernel<<<(NN + 3) / 4, 256, 0, stream>>>(h3, gate_w, gate_b, gate);
    graphagg_kernel<<<BB, 256, 0, stream>>>(gate, h3, bptr, graph);
    proj_kernel<<<BB / 8, 256, 0, stream>>>(graph, proj_w, proj_b, out);
}

// Round 10
// 695.723 us; speedup vs baseline: 1.1047x; 1.1047x over previous
//
#include <hip/hip_runtime.h>
#include <math.h>

#define NN 20000
#define NP 20480   // padded to 160*128 (full supertile groups)
#define EE 60000
#define BB 512
#define HC 1024
#define HH 4
#define CC 256

typedef _Float16 f16;
typedef f16 half8 __attribute__((ext_vector_type(8)));
typedef f16 f16x4 __attribute__((ext_vector_type(4)));
typedef float floatx4 __attribute__((ext_vector_type(4)));
typedef float floatx16 __attribute__((ext_vector_type(16)));

__device__ __forceinline__ void load_lds16(const void* g, void* l) {
    __builtin_amdgcn_global_load_lds((const __attribute__((address_space(1))) void*)g,
                                     (__attribute__((address_space(3))) void*)l, 16, 0, 0);
}

// ---------------- precompute kernels ----------------
__global__ void ea_sum_kernel(const float* __restrict__ ea, float* sums, int E_) {
    float s0 = 0.f, s1 = 0.f, s2 = 0.f;
    for (int e = blockIdx.x * 256 + threadIdx.x; e < E_; e += gridDim.x * 256) {
        s0 += ea[e * 3 + 0];
        s1 += ea[e * 3 + 1];
        s2 += ea[e * 3 + 2];
    }
    for (int o = 32; o; o >>= 1) {
        s0 += __shfl_down(s0, o);
        s1 += __shfl_down(s1, o);
        s2 += __shfl_down(s2, o);
    }
    if ((threadIdx.x & 63) == 0) {
        atomicAdd(&sums[0], s0);
        atomicAdd(&sums[1], s1);
        atomicAdd(&sums[2], s2);
    }
}

__global__ void hist_kernel(const int* __restrict__ ei, int* counts, int E_) {
    int e = blockIdx.x * 256 + threadIdx.x;
    if (e < E_) atomicAdd(&counts[ei[E_ + e]], 1);
}

// two-level scan
__global__ void scan1_kernel(const int* __restrict__ counts, int* __restrict__ partial,
                             int* __restrict__ psums, int n) {
    __shared__ int sdata[256];
    int t = threadIdx.x;
    int i = blockIdx.x * 256 + t;
    int v = (i < n) ? counts[i] : 0;
    sdata[t] = v;
    __syncthreads();
#pragma unroll
    for (int off = 1; off < 256; off <<= 1) {
        int tmp = (t >= off) ? sdata[t - off] : 0;
        __syncthreads();
        sdata[t] += tmp;
        __syncthreads();
    }
    if (i < n) partial[i] = sdata[t];
    if (t == 255) psums[blockIdx.x] = sdata[255];
}

__global__ void scan2_kernel(int* __restrict__ psums, int nb) {
    __shared__ int sdata[128];
    int t = threadIdx.x;
    sdata[t] = (t < nb) ? psums[t] : 0;
    __syncthreads();
#pragma unroll
    for (int off = 1; off < 128; off <<= 1) {
        int tmp = (t >= off) ? sdata[t - off] : 0;
        __syncthreads();
        sdata[t] += tmp;
        __syncthreads();
    }
    if (t < nb) psums[t] = (t == 0) ? 0 : sdata[t - 1];
}

__global__ void scan3_kernel(const int* __restrict__ partial, const int* __restrict__ psums,
                             int* __restrict__ indptr, int n) {
    int i = blockIdx.x * 256 + threadIdx.x;
    if (i == 0) indptr[0] = 0;
    if (i < n) indptr[i + 1] = partial[i] + psums[blockIdx.x];
}

// also records the dst (CSR row) per sorted slot for edge-parallel softmax
__global__ void scatter_kernel(const int* __restrict__ ei, const int* __restrict__ indptr,
                               int* fill, int* sorted, int* sdst, int E_) {
    int e = blockIdx.x * 256 + threadIdx.x;
    if (e >= E_) return;
    int d = ei[E_ + e];
    int pos = indptr[d] + atomicAdd(&fill[d], 1);
    sorted[pos] = e;
    sdst[pos] = d;
}

__global__ void bptr_kernel(const int* __restrict__ batch, int* bptr, int n, int nb) {
    int i = blockIdx.x * 256 + threadIdx.x;
    if (i >= n) return;
    int b = batch[i];
    if (i == 0) {
        for (int bb = 0; bb <= b; bb++) bptr[bb] = 0;
    } else {
        int pb = batch[i - 1];
        if (pb != b) {
            for (int bb = pb + 1; bb <= b; bb++) bptr[bb] = i;
        }
    }
    if (i == n - 1) {
        for (int bb = b + 1; bb <= nb; bb++) bptr[bb] = n;
    }
}

// transpose+convert w_rest[3][1024][1024] fp32 -> wt[3][n][k] fp16 (B^T)
__global__ void wconv_kernel(const float* __restrict__ w_rest, f16* __restrict__ wt) {
    __shared__ float tile[64][65];
    int l = blockIdx.z;
    int bx = blockIdx.x * 64;
    int by = blockIdx.y * 64;
    int t = threadIdx.x;
    int tr = t >> 6, tc = t & 63;
#pragma unroll
    for (int i = 0; i < 16; i++) {
        int r = by + i * 4 + tr;
        tile[i * 4 + tr][tc] = w_rest[(size_t)l * 1048576 + (size_t)r * 1024 + bx + tc];
    }
    __syncthreads();
#pragma unroll
    for (int i = 0; i < 16; i++) {
        int n = bx + i * 4 + tr;
        wt[(size_t)l * 1048576 + (size_t)n * 1024 + by + tc] = (f16)tile[tc][i * 4 + tr];
    }
}

// Mmat[l][d][h]; ae_self[l][h]
__global__ void mmat_all_kernel(const float* __restrict__ w_edge,
                                const float* __restrict__ att_edge,
                                const float* __restrict__ ea_sums, float* Mmat,
                                float* ae_self, float invE) {
    __shared__ float red[256];
    __shared__ float Ms[12];
    int l = blockIdx.x;
    int t = threadIdx.x;
    for (int dh = 0; dh < 12; dh++) {
        int d = dh >> 2, hh = dh & 3;
        float v = w_edge[l * 3072 + d * HC + hh * CC + t] * att_edge[l * HC + hh * CC + t];
        red[t] = v;
        __syncthreads();
        for (int o = 128; o; o >>= 1) {
            if (t < o) red[t] += red[t + o];
            __syncthreads();
        }
        if (t == 0) {
            Ms[dh] = red[0];
            Mmat[l * 12 + dh] = red[0];
        }
        __syncthreads();
    }
    if (t < 4) {
        float v = 0.f;
        for (int d = 0; d < 3; d++) v += ea_sums[d] * invE * Ms[d * 4 + t];
        ae_self[l * 4 + t] = v;
    }
}

// pack CSR
__global__ void pack_kernel(const int* __restrict__ ei, const int* __restrict__ sorted,
                            const float* __restrict__ ea, const float* __restrict__ Mmat,
                            int* __restrict__ ssrc, float* __restrict__ aeh_pk) {
    int idx = blockIdx.x * 256 + threadIdx.x;
    if (idx >= EE) return;
    int eid = sorted[idx];
    ssrc[idx] = ei[eid];
    float a0 = ea[eid * 3 + 0], a1 = ea[eid * 3 + 1], a2 = ea[eid * 3 + 2];
#pragma unroll
    for (int l = 0; l < 4; l++) {
#pragma unroll
        for (int h = 0; h < 4; h++) {
            aeh_pk[(size_t)idx * 16 + l * 4 + h] =
                a0 * Mmat[l * 12 + h] + a1 * Mmat[l * 12 + 4 + h] + a2 * Mmat[l * 12 + 8 + h];
        }
    }
}

// per-layer edge-parallel: pe[idx][h] = exp(leaky(asrc[src]+aeh+adst[dst])) — the final
// softmax numerator, computed ONCE per edge (agg lanes just broadcast-load it).
__global__ void edgep_kernel(const int* __restrict__ ssrc, const int* __restrict__ sdst,
                             const float* __restrict__ aeh_pk, const float* __restrict__ asrc,
                             const float* __restrict__ adst, float* __restrict__ pe,
                             int layer) {
    int i = blockIdx.x * 256 + threadIdx.x;
    if (i >= EE) return;
    int src = ssrc[i];
    int dst = sdst[i];
    float4 a = *(const float4*)&asrc[(size_t)src * 4];
    float4 d = *(const float4*)&adst[(size_t)dst * 4];
    float4 m = *(const float4*)&aeh_pk[(size_t)i * 16 + layer * 4];
    float r[4] = {a.x + d.x + m.x, a.y + d.y + m.y, a.z + d.z + m.z, a.w + d.w + m.w};
    float4 o;
#pragma unroll
    for (int k = 0; k < 4; k++) {
        float v = (r[k] > 0.f) ? r[k] : 0.2f * r[k];
        (&o.x)[k] = __expf(v);
    }
    *(float4*)&pe[(size_t)i * 4] = o;
}

__global__ void bnss_kernel(const float* __restrict__ bias012, const float* __restrict__ bn_g,
                            const float* __restrict__ bn_b, const float* __restrict__ bn_m,
                            const float* __restrict__ bn_v, float2* __restrict__ bnss) {
    int i = blockIdx.x * 256 + threadIdx.x;
    if (i >= 3 * HC) return;
    float s = bn_g[i] * rsqrtf(bn_v[i] + 1e-5f);
    float2 o;
    o.x = s;
    o.y = (bias012[i] - bn_m[i]) * s + bn_b[i];
    bnss[i] = o;
}

__global__ void wvec_kernel(const float* __restrict__ w_rest, const float* __restrict__ att_src,
                            const float* __restrict__ att_dst, float* __restrict__ wsv,
                            float* __restrict__ wdv) {
    int l = blockIdx.y;
    int k = blockIdx.x;
    int t = threadIdx.x;
    int hp = t >> 6, lane = t & 63;
    int col = hp * 256 + lane * 4;
    const float* wrow = w_rest + (size_t)l * 1048576 + (size_t)k * 1024;
    float4 w4 = *(const float4*)&wrow[col];
    float4 a4 = *(const float4*)&att_src[(l + 1) * HC + col];
    float4 d4 = *(const float4*)&att_dst[(l + 1) * HC + col];
    float sp = w4.x * a4.x + w4.y * a4.y + w4.z * a4.z + w4.w * a4.w;
    float dp = w4.x * d4.x + w4.y * d4.y + w4.z * d4.z + w4.w * d4.w;
    for (int m = 1; m < 64; m <<= 1) {
        sp += __shfl_xor(sp, m);
        dp += __shfl_xor(dp, m);
    }
    if (lane == 0) {
        wsv[((size_t)l * 1024 + k) * 4 + hp] = sp;
        wdv[((size_t)l * 1024 + k) * 4 + hp] = dp;
    }
}

__global__ void w0vec_kernel(const float* __restrict__ w0, const float* __restrict__ att_src,
                             const float* __restrict__ att_dst, float* __restrict__ w0s,
                             float* __restrict__ w0d) {
    int f = blockIdx.x;
    int t = threadIdx.x;
    int hp = t >> 6, lane = t & 63;
    int col = hp * 256 + lane * 4;
    float4 w4 = *(const float4*)&w0[f * HC + col];
    float4 a4 = *(const float4*)&att_src[col];
    float4 d4 = *(const float4*)&att_dst[col];
    float sp = w4.x * a4.x + w4.y * a4.y + w4.z * a4.z + w4.w * a4.w;
    float dp = w4.x * d4.x + w4.y * d4.y + w4.z * d4.z + w4.w * d4.w;
    for (int m = 1; m < 64; m <<= 1) {
        sp += __shfl_xor(sp, m);
        dp += __shfl_xor(dp, m);
    }
    if (lane == 0) {
        w0s[f * 4 + hp] = sp;
        w0d[f * 4 + hp] = dp;
    }
}

__global__ void alpha0_kernel(const float* __restrict__ x, const float* __restrict__ w0s,
                              const float* __restrict__ w0d, float* __restrict__ asrc,
                              float* __restrict__ adst) {
    int n = blockIdx.x * 256 + threadIdx.x;
    if (n >= NN) return;
    float xr[7];
#pragma unroll
    for (int f = 0; f < 7; f++) xr[f] = x[n * 7 + f];
#pragma unroll
    for (int hp = 0; hp < 4; hp++) {
        float s = 0.f, d = 0.f;
#pragma unroll
        for (int f = 0; f < 7; f++) {
            s += xr[f] * w0s[f * 4 + hp];
            d += xr[f] * w0d[f * 4 + hp];
        }
        asrc[n * 4 + hp] = s;
        adst[n * 4 + hp] = d;
    }
}

// ---------------- layer 0 (commuted) ----------------
__global__ void agg0x_kernel(const float* __restrict__ x, const float* __restrict__ asrc,
                             const float* __restrict__ adst, const float* __restrict__ ae_self,
                             const int* __restrict__ ssrc, const float* __restrict__ pe,
                             const int* __restrict__ indptr, float* __restrict__ xagg) {
    int n = blockIdx.x * 256 + threadIdx.x;
    if (n >= NN) return;
    float4 as4 = *(const float4*)&asrc[(size_t)n * 4];
    float4 ad4 = *(const float4*)&adst[(size_t)n * 4];
    float adl[4] = {ad4.x, ad4.y, ad4.z, ad4.w};
    float asl[4] = {as4.x, as4.y, as4.z, as4.w};
    float xr[7];
#pragma unroll
    for (int f = 0; f < 7; f++) xr[f] = x[n * 7 + f];
    float denom[4];
    float xa[4][7];
#pragma unroll
    for (int h = 0; h < 4; h++) {
        float r = asl[h] + adl[h] + ae_self[h];
        r = (r > 0.f) ? r : 0.2f * r;
        float p = __expf(r);
        denom[h] = p;
#pragma unroll
        for (int f = 0; f < 7; f++) xa[h][f] = p * xr[f];
    }
    int s = indptr[n], e = indptr[n + 1];
    for (int idx = s; idx < e; idx++) {
        int src = ssrc[idx];
        float4 pv = *(const float4*)&pe[(size_t)idx * 4];
        float pl[4] = {pv.x, pv.y, pv.z, pv.w};
        float xs[7];
#pragma unroll
        for (int f = 0; f < 7; f++) xs[f] = x[src * 7 + f];
#pragma unroll
        for (int h = 0; h < 4; h++) {
            denom[h] += pl[h];
#pragma unroll
            for (int f = 0; f < 7; f++) xa[h][f] += pl[h] * xs[f];
        }
    }
#pragma unroll
    for (int h = 0; h < 4; h++) {
        float inv = 1.0f / (denom[h] + 1e-16f);
#pragma unroll
        for (int f = 0; f < 7; f++) xagg[(size_t)n * 28 + h * 7 + f] = xa[h][f] * inv;
    }
}

__global__ void gemm7f_kernel(const float* __restrict__ xagg, const float* __restrict__ w0,
                              const float2* __restrict__ bnss, const float* __restrict__ wsv,
                              const float* __restrict__ wdv, f16* __restrict__ out16,
                              float* __restrict__ asrc_n, float* __restrict__ adst_n) {
    __shared__ float xs[28];
    __shared__ float red[32];
    int n = blockIdx.x, t = threadIdx.x;
    if (t < 28) xs[t] = xagg[(size_t)n * 28 + t];
    __syncthreads();
    float sp[4] = {0.f, 0.f, 0.f, 0.f}, dp[4] = {0.f, 0.f, 0.f, 0.f};
#pragma unroll
    for (int k = 0; k < 4; k++) {
        int j = k * 256 + t;
        float dot = 0.f;
#pragma unroll
        for (int f = 0; f < 7; f++) dot += xs[k * 7 + f] * w0[f * HC + j];
        float2 ss = bnss[j];
        float val = fmaxf(fmaf(dot, ss.x, ss.y), 0.f);
        out16[(size_t)n * HC + j] = (f16)val;
        float4 w4s = *(const float4*)&wsv[(size_t)j * 4];
        float4 w4d = *(const float4*)&wdv[(size_t)j * 4];
        sp[0] += val * w4s.x; sp[1] += val * w4s.y;
        sp[2] += val * w4s.z; sp[3] += val * w4s.w;
        dp[0] += val * w4d.x; dp[1] += val * w4d.y;
        dp[2] += val * w4d.z; dp[3] += val * w4d.w;
    }
    int wave = t >> 6, lane = t & 63;
#pragma unroll
    for (int m = 1; m < 64; m <<= 1) {
#pragma unroll
        for (int j = 0; j < 4; j++) {
            sp[j] += __shfl_xor(sp[j], m);
            dp[j] += __shfl_xor(dp[j], m);
        }
    }
    if (lane == 0) {
#pragma unroll
        for (int j = 0; j < 4; j++) {
            red[wave * 8 + j] = sp[j];
            red[wave * 8 + 4 + j] = dp[j];
        }
    }
    __syncthreads();
    if (t < 8) {
        float v = red[t] + red[8 + t] + red[16 + t] + red[24 + t];
        if (t < 4) asrc_n[n * 4 + t] = v;
        else adst_n[n * 4 + (t - 4)] = v;
    }
}

// ---------------- GEMM (layers 1-3) ----------------
// Single-buffer BK=32/16KB LDS (R8 known-good: dbuf measured neutral, m99/m100-style).
// 32x32x16 MFMA operand-swapped epilogue; L2 supertile 8m x 8n; M padded.
__global__ __launch_bounds__(256) void mfma_gemm_kernel(const f16* __restrict__ A,
                                                        const f16* __restrict__ Bt,
                                                        f16* __restrict__ C16,
                                                        int N, int K) {
    __shared__ f16 As[4 * 128 * 8];
    __shared__ f16 Bs[4 * 128 * 8];
    int t = threadIdx.x;
    int wave = t >> 6, lane = t & 63;
    int wr = (wave >> 1) * 64;
    int wc = (wave & 1) * 64;
    int gid = blockIdx.x;
    int g = gid >> 6;
    int rblk = gid & 63;
    int n0 = (rblk >> 3) * 128;
    int m0 = (g * 8 + (rblk & 7)) * 128;

    floatx16 acc[2][2];
#pragma unroll
    for (int i = 0; i < 2; i++)
#pragma unroll
        for (int j = 0; j < 2; j++) acc[i][j] = (floatx16)(0.f);

    int q0 = t >> 7, r0 = t & 127;
    int q1 = (256 + t) >> 7, r1 = (256 + t) & 127;
    const f16* pa0 = A + (size_t)(m0 + r0) * K + q0 * 8;
    const f16* pa1 = A + (size_t)(m0 + r1) * K + q1 * 8;
    const f16* pb0 = Bt + (size_t)(n0 + r0) * K + q0 * 8;
    const f16* pb1 = Bt + (size_t)(n0 + r1) * K + q1 * 8;
    f16* la0 = As + (size_t)t * 8;
    f16* la1 = As + (size_t)(256 + t) * 8;
    f16* lb0 = Bs + (size_t)t * 8;
    f16* lb1 = Bs + (size_t)(256 + t) * 8;

    int fr32 = lane & 31, kg = lane >> 5;

    for (int k0 = 0; k0 < K; k0 += 32) {
        __syncthreads();
        load_lds16(pa0 + k0, la0);
        load_lds16(pa1 + k0, la1);
        load_lds16(pb0 + k0, lb0);
        load_lds16(pb1 + k0, lb1);
        __syncthreads();
#pragma unroll
        for (int kh = 0; kh < 2; kh++) {
            half8 af[2], bf[2];
#pragma unroll
            for (int i = 0; i < 2; i++)
                af[i] = *(const half8*)&As[((kh * 2 + kg) * 128 + wr + i * 32 + fr32) * 8];
#pragma unroll
            for (int j = 0; j < 2; j++)
                bf[j] = *(const half8*)&Bs[((kh * 2 + kg) * 128 + wc + j * 32 + fr32) * 8];
#pragma unroll
            for (int i = 0; i < 2; i++)
#pragma unroll
                for (int j = 0; j < 2; j++)
                    acc[i][j] = __builtin_amdgcn_mfma_f32_32x32x16_f16(bf[j], af[i],
                                                                       acc[i][j], 0, 0, 0);
        }
    }

#pragma unroll
    for (int i = 0; i < 2; i++) {
        int row = m0 + wr + i * 32 + fr32;
#pragma unroll
        for (int j = 0; j < 2; j++) {
#pragma unroll
            for (int gq = 0; gq < 4; gq++) {
                f16x4 o;
#pragma unroll
                for (int r = 0; r < 4; r++) o[r] = (f16)acc[i][j][gq * 4 + r];
                *(f16x4*)&C16[(size_t)row * N + n0 + wc + j * 32 + gq * 8 + kg * 4] = o;
            }
        }
    }
}

// ---------------- fused attention + aggregation (block per node, chunk-4) ----------
// pe precomputed per edge (edgep): inner loop = broadcast pe + row gather + FMA only.
// Layer 3 also fuses the gate dot-product.
__global__ void agg_kernel(const f16* __restrict__ h16, const float* __restrict__ asrc,
                           const float* __restrict__ adst, const float* __restrict__ ae_self,
                           const int* __restrict__ ssrc, const float* __restrict__ pe,
                           const int* __restrict__ indptr, const float2* __restrict__ bnss,
                           const float* __restrict__ wsv, const float* __restrict__ wdv,
                           const float* __restrict__ bias3, const float* __restrict__ gw,
                           const float* __restrict__ gb, f16* __restrict__ out16,
                           float* __restrict__ asrc_n, float* __restrict__ adst_n,
                           float* __restrict__ out3, float* __restrict__ gate,
                           int layer, int concat) {
    __shared__ float buf[1024];
    __shared__ float red[32];
    int n = blockIdx.x, t = threadIdx.x;
    int h = t >> 6, lane = t & 63;
    int c4 = t * 4;

    float r = asrc[n * 4 + h] + adst[n * 4 + h] + ae_self[layer * 4 + h];
    r = (r > 0.f) ? r : 0.2f * r;
    float p = __expf(r);
    float denom = p;
    float ax, ay, az, aw;
    {
        f16x4 v = *(const f16x4*)&h16[(size_t)n * HC + c4];
        ax = p * (float)v[0]; ay = p * (float)v[1];
        az = p * (float)v[2]; aw = p * (float)v[3];
    }
    int s = indptr[n], epos = indptr[n + 1];
    for (int base = s; base < epos; base += 4) {
        int rem = epos - base;
        int src[4];
        float pv[4];
#pragma unroll
        for (int j = 0; j < 4; j++) {
            if (j < rem) {
                src[j] = ssrc[base + j];
                pv[j] = pe[(size_t)(base + j) * 4 + h];
            } else {
                src[j] = n;
                pv[j] = 0.f;
            }
        }
        f16x4 u[4];
#pragma unroll
        for (int j = 0; j < 4; j++) u[j] = *(const f16x4*)&h16[(size_t)src[j] * HC + c4];
#pragma unroll
        for (int j = 0; j < 4; j++) {
            denom += pv[j];
            ax += pv[j] * (float)u[j][0];
            ay += pv[j] * (float)u[j][1];
            az += pv[j] * (float)u[j][2];
            aw += pv[j] * (float)u[j][3];
        }
    }
    float inv = 1.0f / (denom + 1e-16f);
    ax *= inv; ay *= inv; az *= inv; aw *= inv;

    if (concat) {
        float vals[4] = {ax, ay, az, aw};
        f16x4 o;
        float sp[4] = {0.f, 0.f, 0.f, 0.f}, dp[4] = {0.f, 0.f, 0.f, 0.f};
#pragma unroll
        for (int k = 0; k < 4; k++) {
            int j = c4 + k;
            float2 ss = bnss[j];
            float val = fmaxf(fmaf(vals[k], ss.x, ss.y), 0.f);
            o[k] = (f16)val;
            float4 w4s = *(const float4*)&wsv[(size_t)j * 4];
            float4 w4d = *(const float4*)&wdv[(size_t)j * 4];
            sp[0] += val * w4s.x; sp[1] += val * w4s.y;
            sp[2] += val * w4s.z; sp[3] += val * w4s.w;
            dp[0] += val * w4d.x; dp[1] += val * w4d.y;
            dp[2] += val * w4d.z; dp[3] += val * w4d.w;
        }
        *(f16x4*)&out16[(size_t)n * HC + c4] = o;
#pragma unroll
        for (int m = 1; m < 64; m <<= 1) {
#pragma unroll
            for (int j = 0; j < 4; j++) {
                sp[j] += __shfl_xor(sp[j], m);
                dp[j] += __shfl_xor(dp[j], m);
            }
        }
        if (lane == 0) {
#pragma unroll
            for (int j = 0; j < 4; j++) {
                red[h * 8 + j] = sp[j];
                red[h * 8 + 4 + j] = dp[j];
            }
        }
        __syncthreads();
        if (t < 8) {
            float v = red[t] + red[8 + t] + red[16 + t] + red[24 + t];
            if (t < 4) asrc_n[n * 4 + t] = v;
            else adst_n[n * 4 + (t - 4)] = v;
        }
    } else {
        buf[c4 + 0] = ax;
        buf[c4 + 1] = ay;
        buf[c4 + 2] = az;
        buf[c4 + 3] = aw;
        __syncthreads();
        if (t < 64) {
            float gpart = 0.f;
#pragma unroll
            for (int k = 0; k < 4; k++) {
                int c = t * 4 + k;
                float v2 = 0.25f * (buf[c] + buf[256 + c] + buf[512 + c] + buf[768 + c]) +
                           bias3[c];
                out3[(size_t)n * CC + c] = v2;
                gpart += v2 * gw[c];
            }
            for (int o = 32; o; o >>= 1) gpart += __shfl_down(gpart, o);
            if (t == 0) gate[n] = gpart + gb[0];
        }
    }
}

// ---------------- readout ----------------
__global__ void graphagg_kernel(const float* __restrict__ gate, const float* __restrict__ h3,
                                const int* __restrict__ bptr, float* __restrict__ graph) {
    __shared__ float red[256];
    __shared__ float wn[256];
    int b = blockIdx.x, t = threadIdx.x;
    int s = bptr[b], epos = bptr[b + 1];
    float m = -3.4e38f;
    for (int n = s + t; n < epos; n += 256) m = fmaxf(m, gate[n]);
    red[t] = m;
    __syncthreads();
    for (int o = 128; o; o >>= 1) {
        if (t < o) red[t] = fmaxf(red[t], red[t + o]);
        __syncthreads();
    }
    float mval = red[0];
    __syncthreads();
    float sum = 0.f;
    for (int n = s + t; n < epos; n += 256) sum += __expf(gate[n] - mval);
    red[t] = sum;
    __syncthreads();
    for (int o = 128; o; o >>= 1) {
        if (t < o) red[t] += red[t + o];
        __syncthreads();
    }
    float ssum = red[0];
    __syncthreads();
    float acc = 0.f;
    for (int base = s; base < epos; base += 256) {
        int n = base + t;
        wn[t] = (n < epos) ? __expf(gate[n] - mval) : 0.f;
        __syncthreads();
        int cnt = min(256, epos - base);
        for (int j = 0; j < cnt; j++) acc += wn[j] * h3[(size_t)(base + j) * CC + t];
        __syncthreads();
    }
    graph[b * CC + t] = acc / (ssum + 1e-16f);
}

__global__ void proj_kernel(const float* __restrict__ graph, const float* __restrict__ pw,
                            const float* __restrict__ pb, float* __restrict__ out) {
    __shared__ float g[256];
    int b = blockIdx.x, t = threadIdx.x;
    g[t] = graph[b * CC + t];
    __syncthreads();
    for (int j = t; j < 1024; j += 256) {
        float acc = pb[j];
        for (int c = 0; c < 256; c++) acc += g[c] * pw[c * 1024 + j];
        out[(size_t)b * 1024 + j] = acc;
    }
}

// ---------------- host ----------------
extern "C" void kernel_launch(void* const* d_in, const int* in_sizes, int n_in,
                              void* d_out, int out_size, void* d_ws, size_t ws_size,
                              hipStream_t stream) {
    const float* x = (const float*)d_in[0];
    const int* ei = (const int*)d_in[1];
    const float* ea = (const float*)d_in[2];
    const int* batch = (const int*)d_in[3];
    const float* w0 = (const float*)d_in[4];
    const float* w_rest = (const float*)d_in[5];
    const float* w_edge = (const float*)d_in[6];
    const float* att_src = (const float*)d_in[7];
    const float* att_dst = (const float*)d_in[8];
    const float* att_edge = (const float*)d_in[9];
    const float* bias012 = (const float*)d_in[10];
    const float* bias3 = (const float*)d_in[11];
    const float* bn_g = (const float*)d_in[12];
    const float* bn_b = (const float*)d_in[13];
    const float* bn_m = (const float*)d_in[14];
    const float* bn_v = (const float*)d_in[15];
    const float* gate_w = (const float*)d_in[16];
    const float* gate_b = (const float*)d_in[17];
    const float* proj_w = (const float*)d_in[18];
    const float* proj_b = (const float*)d_in[19];
    float* out = (float*)d_out;

    float* ws = (float*)d_ws;
    size_t off = 0;
    f16* h_lin = (f16*)(ws + off); off += (size_t)NP * HC / 2;
    f16* h_in = (f16*)(ws + off); off += (size_t)NP * HC / 2;
    float* h3 = ws + off; off += (size_t)NN * CC;
    f16* wt = (f16*)(ws + off); off += (size_t)3 * HC * HC / 2;
    float* asrcA = ws + off; off += (size_t)NN * 4;
    float* adstA = ws + off; off += (size_t)NN * 4;
    float* asrcB = ws + off; off += (size_t)NN * 4;
    float* adstB = ws + off; off += (size_t)NN * 4;
    float* wsv = ws + off; off += (size_t)3 * HC * 4;
    float* wdv = ws + off; off += (size_t)3 * HC * 4;
    float* w0s = ws + off; off += 28;
    float* w0d = ws + off; off += 28;
    float2* bnss = (float2*)(ws + off); off += (size_t)3 * HC * 2;
    float* aeh_pk = ws + off; off += (size_t)EE * 16;
    float* pbuf = ws + off; off += (size_t)EE * 4;
    float* xagg = ws + off; off += (size_t)NN * 28;
    float* gate = ws + off; off += (size_t)NN;
    float* graph = ws + off; off += (size_t)BB * CC;
    float* ea_sums = ws + off; off += 4;
    float* Mmat = ws + off; off += 48;
    float* ae_self = ws + off; off += 16;
    int* counts = (int*)(ws + off); off += NN;
    int* partial = (int*)(ws + off); off += NN;
    int* psums = (int*)(ws + off); off += 128;
    int* indptr = (int*)(ws + off); off += NN + 1;
    int* fill = (int*)(ws + off); off += NN;
    int* sorted = (int*)(ws + off); off += EE;
    int* ssrc = (int*)(ws + off); off += EE;
    int* sdst = (int*)(ws + off); off += EE;
    int* bptr = (int*)(ws + off); off += BB + 1;

    hipMemsetAsync(ea_sums, 0, 4 * sizeof(float), stream);
    hipMemsetAsync(counts, 0, NN * sizeof(int), stream);
    hipMemsetAsync(fill, 0, NN * sizeof(int), stream);

    ea_sum_kernel<<<64, 256, 0, stream>>>(ea, ea_sums, EE);
    hist_kernel<<<(EE + 255) / 256, 256, 0, stream>>>(ei, counts, EE);
    int nblk = (NN + 255) / 256;  // 79
    scan1_kernel<<<nblk, 256, 0, stream>>>(counts, partial, psums, NN);
    scan2_kernel<<<1, 128, 0, stream>>>(psums, nblk);
    scan3_kernel<<<nblk, 256, 0, stream>>>(partial, psums, indptr, NN);
    scatter_kernel<<<(EE + 255) / 256, 256, 0, stream>>>(ei, indptr, fill, sorted, sdst, EE);
    bptr_kernel<<<(NN + 255) / 256, 256, 0, stream>>>(batch, bptr, NN, BB);
    wconv_kernel<<<dim3(16, 16, 3), 256, 0, stream>>>(w_rest, wt);
    mmat_all_kernel<<<4, 256, 0, stream>>>(w_edge, att_edge, ea_sums, Mmat, ae_self,
                                           1.0f / EE);
    pack_kernel<<<(EE + 255) / 256, 256, 0, stream>>>(ei, sorted, ea, Mmat, ssrc, aeh_pk);
    bnss_kernel<<<(3 * HC + 255) / 256, 256, 0, stream>>>(bias012, bn_g, bn_b, bn_m, bn_v,
                                                          bnss);
    wvec_kernel<<<dim3(1024, 3), 256, 0, stream>>>(w_rest, att_src, att_dst, wsv, wdv);
    w0vec_kernel<<<7, 256, 0, stream>>>(w0, att_src, att_dst, w0s, w0d);
    alpha0_kernel<<<(NN + 255) / 256, 256, 0, stream>>>(x, w0s, w0d, asrcA, adstA);

    // ---- layer 0 (commuted) ----
    edgep_kernel<<<(EE + 255) / 256, 256, 0, stream>>>(ssrc, sdst, aeh_pk, asrcA, adstA,
                                                       pbuf, 0);
    agg0x_kernel<<<(NN + 255) / 256, 256, 0, stream>>>(x, asrcA, adstA, ae_self, ssrc,
                                                       pbuf, indptr, xagg);
    gemm7f_kernel<<<NN, 256, 0, stream>>>(xagg, w0, bnss, wsv, wdv, h_in, asrcB, adstB);

    float* asrc_cur = asrcB;
    float* adst_cur = adstB;
    float* asrc_nxt = asrcA;
    float* adst_nxt = adstA;
    for (int i = 1; i < 4; i++) {
        mfma_gemm_kernel<<<(NP / 128) * (HC / 128), 256, 0, stream>>>(
            h_in, wt + (size_t)(i - 1) * HC * HC, h_lin, HC, HC);
        edgep_kernel<<<(EE + 255) / 256, 256, 0, stream>>>(ssrc, sdst, aeh_pk, asrc_cur,
                                                           adst_cur, pbuf, i);
        agg_kernel<<<NN, 256, 0, stream>>>(
            h_lin, asrc_cur, adst_cur, ae_self, ssrc, pbuf, indptr, bnss + (size_t)i * HC,
            wsv + (size_t)i * HC * 4, wdv + (size_t)i * HC * 4, bias3, gate_w, gate_b,
            h_in, asrc_nxt, adst_nxt, h3, gate, i, (i < 3) ? 1 : 0);
        float* tmp = asrc_cur; asrc_cur = asrc_nxt; asrc_nxt = tmp;
        tmp = adst_cur; adst_cur = adst_nxt; adst_nxt = tmp;
    }

    graphagg_kernel<<<BB, 256, 0, stream>>>(gate, h3, bptr, graph);
    proj_kernel<<<BB, 256, 0, stream>>>(graph, proj_w, proj_b, out);
}

// Round 11
// 664.389 us; speedup vs baseline: 1.1568x; 1.0472x over previous
//
#include <hip/hip_runtime.h>
#include <math.h>

#define NN 20000
#define NP 20480   // padded to 160*128 (full supertile groups)
#define EE 60000
#define BB 512
#define HC 1024
#define HH 4
#define CC 256

typedef _Float16 f16;
typedef f16 half8 __attribute__((ext_vector_type(8)));
typedef f16 f16x4 __attribute__((ext_vector_type(4)));
typedef float floatx4 __attribute__((ext_vector_type(4)));
typedef float floatx16 __attribute__((ext_vector_type(16)));

// A-fragment (and B-fragment) layout for barrier-free GEMM:
// Af[mblk][iter][kh][rg][kg*32+lr][e] = A[mblk*128 + rg*32 + lr][iter*32 + (kh*2+kg)*8 + e]
__device__ __forceinline__ size_t af_off(int n, int c) {
    int mblk = n >> 7, rr = n & 127;
    int iter = c >> 5, kc = c & 31;
    int kh = kc >> 4, kg = (kc >> 3) & 1, e = kc & 7;
    return ((((size_t)(mblk * 32 + iter) * 2 + kh) * 4 + (rr >> 5)) * 64 +
            (kg * 32 + (rr & 31))) * 8 + e;
}

// ---------------- precompute kernels ----------------
__global__ void ea_sum_kernel(const float* __restrict__ ea, float* sums, int E_) {
    float s0 = 0.f, s1 = 0.f, s2 = 0.f;
    for (int e = blockIdx.x * 256 + threadIdx.x; e < E_; e += gridDim.x * 256) {
        s0 += ea[e * 3 + 0];
        s1 += ea[e * 3 + 1];
        s2 += ea[e * 3 + 2];
    }
    for (int o = 32; o; o >>= 1) {
        s0 += __shfl_down(s0, o);
        s1 += __shfl_down(s1, o);
        s2 += __shfl_down(s2, o);
    }
    if ((threadIdx.x & 63) == 0) {
        atomicAdd(&sums[0], s0);
        atomicAdd(&sums[1], s1);
        atomicAdd(&sums[2], s2);
    }
}

__global__ void hist_kernel(const int* __restrict__ ei, int* counts, int E_) {
    int e = blockIdx.x * 256 + threadIdx.x;
    if (e < E_) atomicAdd(&counts[ei[E_ + e]], 1);
}

// two-level scan
__global__ void scan1_kernel(const int* __restrict__ counts, int* __restrict__ partial,
                             int* __restrict__ psums, int n) {
    __shared__ int sdata[256];
    int t = threadIdx.x;
    int i = blockIdx.x * 256 + t;
    int v = (i < n) ? counts[i] : 0;
    sdata[t] = v;
    __syncthreads();
#pragma unroll
    for (int off = 1; off < 256; off <<= 1) {
        int tmp = (t >= off) ? sdata[t - off] : 0;
        __syncthreads();
        sdata[t] += tmp;
        __syncthreads();
    }
    if (i < n) partial[i] = sdata[t];
    if (t == 255) psums[blockIdx.x] = sdata[255];
}

__global__ void scan2_kernel(int* __restrict__ psums, int nb) {
    __shared__ int sdata[128];
    int t = threadIdx.x;
    sdata[t] = (t < nb) ? psums[t] : 0;
    __syncthreads();
#pragma unroll
    for (int off = 1; off < 128; off <<= 1) {
        int tmp = (t >= off) ? sdata[t - off] : 0;
        __syncthreads();
        sdata[t] += tmp;
        __syncthreads();
    }
    if (t < nb) psums[t] = (t == 0) ? 0 : sdata[t - 1];
}

__global__ void scan3_kernel(const int* __restrict__ partial, const int* __restrict__ psums,
                             int* __restrict__ indptr, int n) {
    int i = blockIdx.x * 256 + threadIdx.x;
    if (i == 0) indptr[0] = 0;
    if (i < n) indptr[i + 1] = partial[i] + psums[blockIdx.x];
}

__global__ void scatter_kernel(const int* __restrict__ ei, const int* __restrict__ indptr,
                               int* fill, int* sorted, int* sdst, int E_) {
    int e = blockIdx.x * 256 + threadIdx.x;
    if (e >= E_) return;
    int d = ei[E_ + e];
    int pos = indptr[d] + atomicAdd(&fill[d], 1);
    sorted[pos] = e;
    sdst[pos] = d;
}

__global__ void bptr_kernel(const int* __restrict__ batch, int* bptr, int n, int nb) {
    int i = blockIdx.x * 256 + threadIdx.x;
    if (i >= n) return;
    int b = batch[i];
    if (i == 0) {
        for (int bb = 0; bb <= b; bb++) bptr[bb] = 0;
    } else {
        int pb = batch[i - 1];
        if (pb != b) {
            for (int bb = pb + 1; bb <= b; bb++) bptr[bb] = i;
        }
    }
    if (i == n - 1) {
        for (int bb = b + 1; bb <= nb; bb++) bptr[bb] = n;
    }
}

// transpose+convert w_rest[3][1024][1024] fp32 -> wt[3][n][k] fp16 (B^T)
__global__ void wconv_kernel(const float* __restrict__ w_rest, f16* __restrict__ wt) {
    __shared__ float tile[64][65];
    int l = blockIdx.z;
    int bx = blockIdx.x * 64;
    int by = blockIdx.y * 64;
    int t = threadIdx.x;
    int tr = t >> 6, tc = t & 63;
#pragma unroll
    for (int i = 0; i < 16; i++) {
        int r = by + i * 4 + tr;
        tile[i * 4 + tr][tc] = w_rest[(size_t)l * 1048576 + (size_t)r * 1024 + bx + tc];
    }
    __syncthreads();
#pragma unroll
    for (int i = 0; i < 16; i++) {
        int n = bx + i * 4 + tr;
        wt[(size_t)l * 1048576 + (size_t)n * 1024 + by + tc] = (f16)tile[tc][i * 4 + tr];
    }
}

// reshape wt (B^T row-major) -> Bf fragment-major (one-time, 2MB/layer)
__global__ void bfrs_kernel(const f16* __restrict__ wt, f16* __restrict__ Bf) {
    int iter = blockIdx.x, nblk = blockIdx.y, l = blockIdx.z;
    const f16* wl = wt + (size_t)l * 1048576;
    f16* bl = Bf + (size_t)l * 1048576;
    int t = threadIdx.x;
    for (int c = t; c < 512; c += 256) {
        int kh = c >> 8, rem = c & 255, cg = rem >> 6, lane = rem & 63;
        int n = nblk * 128 + cg * 32 + (lane & 31);
        int k = iter * 32 + (kh * 2 + (lane >> 5)) * 8;
        half8 v = *(const half8*)&wl[(size_t)n * 1024 + k];
        *(half8*)&bl[(size_t)(nblk * 32 + iter) * 4096 + c * 8] = v;
    }
}

// Mmat[l][d][h]; ae_self[l][h]
__global__ void mmat_all_kernel(const float* __restrict__ w_edge,
                                const float* __restrict__ att_edge,
                                const float* __restrict__ ea_sums, float* Mmat,
                                float* ae_self, float invE) {
    __shared__ float red[256];
    __shared__ float Ms[12];
    int l = blockIdx.x;
    int t = threadIdx.x;
    for (int dh = 0; dh < 12; dh++) {
        int d = dh >> 2, hh = dh & 3;
        float v = w_edge[l * 3072 + d * HC + hh * CC + t] * att_edge[l * HC + hh * CC + t];
        red[t] = v;
        __syncthreads();
        for (int o = 128; o; o >>= 1) {
            if (t < o) red[t] += red[t + o];
            __syncthreads();
        }
        if (t == 0) {
            Ms[dh] = red[0];
            Mmat[l * 12 + dh] = red[0];
        }
        __syncthreads();
    }
    if (t < 4) {
        float v = 0.f;
        for (int d = 0; d < 3; d++) v += ea_sums[d] * invE * Ms[d * 4 + t];
        ae_self[l * 4 + t] = v;
    }
}

// pack CSR
__global__ void pack_kernel(const int* __restrict__ ei, const int* __restrict__ sorted,
                            const float* __restrict__ ea, const float* __restrict__ Mmat,
                            int* __restrict__ ssrc, float* __restrict__ aeh_pk) {
    int idx = blockIdx.x * 256 + threadIdx.x;
    if (idx >= EE) return;
    int eid = sorted[idx];
    ssrc[idx] = ei[eid];
    float a0 = ea[eid * 3 + 0], a1 = ea[eid * 3 + 1], a2 = ea[eid * 3 + 2];
#pragma unroll
    for (int l = 0; l < 4; l++) {
#pragma unroll
        for (int h = 0; h < 4; h++) {
            aeh_pk[(size_t)idx * 16 + l * 4 + h] =
                a0 * Mmat[l * 12 + h] + a1 * Mmat[l * 12 + 4 + h] + a2 * Mmat[l * 12 + 8 + h];
        }
    }
}

// per-layer edge-parallel softmax numerator
__global__ void edgep_kernel(const int* __restrict__ ssrc, const int* __restrict__ sdst,
                             const float* __restrict__ aeh_pk, const float* __restrict__ asrc,
                             const float* __restrict__ adst, float* __restrict__ pe,
                             int layer) {
    int i = blockIdx.x * 256 + threadIdx.x;
    if (i >= EE) return;
    int src = ssrc[i];
    int dst = sdst[i];
    float4 a = *(const float4*)&asrc[(size_t)src * 4];
    float4 d = *(const float4*)&adst[(size_t)dst * 4];
    float4 m = *(const float4*)&aeh_pk[(size_t)i * 16 + layer * 4];
    float r[4] = {a.x + d.x + m.x, a.y + d.y + m.y, a.z + d.z + m.z, a.w + d.w + m.w};
    float4 o;
#pragma unroll
    for (int k = 0; k < 4; k++) {
        float v = (r[k] > 0.f) ? r[k] : 0.2f * r[k];
        (&o.x)[k] = __expf(v);
    }
    *(float4*)&pe[(size_t)i * 4] = o;
}

__global__ void bnss_kernel(const float* __restrict__ bias012, const float* __restrict__ bn_g,
                            const float* __restrict__ bn_b, const float* __restrict__ bn_m,
                            const float* __restrict__ bn_v, float2* __restrict__ bnss) {
    int i = blockIdx.x * 256 + threadIdx.x;
    if (i >= 3 * HC) return;
    float s = bn_g[i] * rsqrtf(bn_v[i] + 1e-5f);
    float2 o;
    o.x = s;
    o.y = (bias012[i] - bn_m[i]) * s + bn_b[i];
    bnss[i] = o;
}

__global__ void wvec_kernel(const float* __restrict__ w_rest, const float* __restrict__ att_src,
                            const float* __restrict__ att_dst, float* __restrict__ wsv,
                            float* __restrict__ wdv) {
    int l = blockIdx.y;
    int k = blockIdx.x;
    int t = threadIdx.x;
    int hp = t >> 6, lane = t & 63;
    int col = hp * 256 + lane * 4;
    const float* wrow = w_rest + (size_t)l * 1048576 + (size_t)k * 1024;
    float4 w4 = *(const float4*)&wrow[col];
    float4 a4 = *(const float4*)&att_src[(l + 1) * HC + col];
    float4 d4 = *(const float4*)&att_dst[(l + 1) * HC + col];
    float sp = w4.x * a4.x + w4.y * a4.y + w4.z * a4.z + w4.w * a4.w;
    float dp = w4.x * d4.x + w4.y * d4.y + w4.z * d4.z + w4.w * d4.w;
    for (int m = 1; m < 64; m <<= 1) {
        sp += __shfl_xor(sp, m);
        dp += __shfl_xor(dp, m);
    }
    if (lane == 0) {
        wsv[((size_t)l * 1024 + k) * 4 + hp] = sp;
        wdv[((size_t)l * 1024 + k) * 4 + hp] = dp;
    }
}

__global__ void w0vec_kernel(const float* __restrict__ w0, const float* __restrict__ att_src,
                             const float* __restrict__ att_dst, float* __restrict__ w0s,
                             float* __restrict__ w0d) {
    int f = blockIdx.x;
    int t = threadIdx.x;
    int hp = t >> 6, lane = t & 63;
    int col = hp * 256 + lane * 4;
    float4 w4 = *(const float4*)&w0[f * HC + col];
    float4 a4 = *(const float4*)&att_src[col];
    float4 d4 = *(const float4*)&att_dst[col];
    float sp = w4.x * a4.x + w4.y * a4.y + w4.z * a4.z + w4.w * a4.w;
    float dp = w4.x * d4.x + w4.y * d4.y + w4.z * d4.z + w4.w * d4.w;
    for (int m = 1; m < 64; m <<= 1) {
        sp += __shfl_xor(sp, m);
        dp += __shfl_xor(dp, m);
    }
    if (lane == 0) {
        w0s[f * 4 + hp] = sp;
        w0d[f * 4 + hp] = dp;
    }
}

__global__ void alpha0_kernel(const float* __restrict__ x, const float* __restrict__ w0s,
                              const float* __restrict__ w0d, float* __restrict__ asrc,
                              float* __restrict__ adst) {
    int n = blockIdx.x * 256 + threadIdx.x;
    if (n >= NN) return;
    float xr[7];
#pragma unroll
    for (int f = 0; f < 7; f++) xr[f] = x[n * 7 + f];
#pragma unroll
    for (int hp = 0; hp < 4; hp++) {
        float s = 0.f, d = 0.f;
#pragma unroll
        for (int f = 0; f < 7; f++) {
            s += xr[f] * w0s[f * 4 + hp];
            d += xr[f] * w0d[f * 4 + hp];
        }
        asrc[n * 4 + hp] = s;
        adst[n * 4 + hp] = d;
    }
}

// ---------------- layer 0 (commuted) ----------------
__global__ void agg0x_kernel(const float* __restrict__ x, const float* __restrict__ asrc,
                             const float* __restrict__ adst, const float* __restrict__ ae_self,
                             const int* __restrict__ ssrc, const float* __restrict__ pe,
                             const int* __restrict__ indptr, float* __restrict__ xagg) {
    int n = blockIdx.x * 256 + threadIdx.x;
    if (n >= NN) return;
    float4 as4 = *(const float4*)&asrc[(size_t)n * 4];
    float4 ad4 = *(const float4*)&adst[(size_t)n * 4];
    float adl[4] = {ad4.x, ad4.y, ad4.z, ad4.w};
    float asl[4] = {as4.x, as4.y, as4.z, as4.w};
    float xr[7];
#pragma unroll
    for (int f = 0; f < 7; f++) xr[f] = x[n * 7 + f];
    float denom[4];
    float xa[4][7];
#pragma unroll
    for (int h = 0; h < 4; h++) {
        float r = asl[h] + adl[h] + ae_self[h];
        r = (r > 0.f) ? r : 0.2f * r;
        float p = __expf(r);
        denom[h] = p;
#pragma unroll
        for (int f = 0; f < 7; f++) xa[h][f] = p * xr[f];
    }
    int s = indptr[n], e = indptr[n + 1];
    for (int idx = s; idx < e; idx++) {
        int src = ssrc[idx];
        float4 pv = *(const float4*)&pe[(size_t)idx * 4];
        float pl[4] = {pv.x, pv.y, pv.z, pv.w};
        float xs[7];
#pragma unroll
        for (int f = 0; f < 7; f++) xs[f] = x[src * 7 + f];
#pragma unroll
        for (int h = 0; h < 4; h++) {
            denom[h] += pl[h];
#pragma unroll
            for (int f = 0; f < 7; f++) xa[h][f] += pl[h] * xs[f];
        }
    }
#pragma unroll
    for (int h = 0; h < 4; h++) {
        float inv = 1.0f / (denom[h] + 1e-16f);
#pragma unroll
        for (int f = 0; f < 7; f++) xagg[(size_t)n * 28 + h * 7 + f] = xa[h][f] * inv;
    }
}

// h_act = relu(BN(xagg @ w0)) written in Af fragment layout + next-layer alpha epilogue
__global__ void gemm7f_kernel(const float* __restrict__ xagg, const float* __restrict__ w0,
                              const float2* __restrict__ bnss, const float* __restrict__ wsv,
                              const float* __restrict__ wdv, f16* __restrict__ outAf,
                              float* __restrict__ asrc_n, float* __restrict__ adst_n) {
    __shared__ float xs[28];
    __shared__ float red[32];
    int n = blockIdx.x, t = threadIdx.x;
    if (t < 28) xs[t] = xagg[(size_t)n * 28 + t];
    __syncthreads();
    int head = t >> 6;
    int j0 = t * 4;
    float sp[4] = {0.f, 0.f, 0.f, 0.f}, dp[4] = {0.f, 0.f, 0.f, 0.f};
    f16x4 o;
#pragma unroll
    for (int k = 0; k < 4; k++) {
        int j = j0 + k;
        float dot = 0.f;
#pragma unroll
        for (int f = 0; f < 7; f++) dot += xs[head * 7 + f] * w0[f * HC + j];
        float2 ss = bnss[j];
        float val = fmaxf(fmaf(dot, ss.x, ss.y), 0.f);
        o[k] = (f16)val;
        float4 w4s = *(const float4*)&wsv[(size_t)j * 4];
        float4 w4d = *(const float4*)&wdv[(size_t)j * 4];
        sp[0] += val * w4s.x; sp[1] += val * w4s.y;
        sp[2] += val * w4s.z; sp[3] += val * w4s.w;
        dp[0] += val * w4d.x; dp[1] += val * w4d.y;
        dp[2] += val * w4d.z; dp[3] += val * w4d.w;
    }
    *(f16x4*)&outAf[af_off(n, j0)] = o;
    int wave = t >> 6, lane = t & 63;
#pragma unroll
    for (int m = 1; m < 64; m <<= 1) {
#pragma unroll
        for (int j = 0; j < 4; j++) {
            sp[j] += __shfl_xor(sp[j], m);
            dp[j] += __shfl_xor(dp[j], m);
        }
    }
    if (lane == 0) {
#pragma unroll
        for (int j = 0; j < 4; j++) {
            red[wave * 8 + j] = sp[j];
            red[wave * 8 + 4 + j] = dp[j];
        }
    }
    __syncthreads();
    if (t < 8) {
        float v = red[t] + red[8 + t] + red[16 + t] + red[24 + t];
        if (t < 4) asrc_n[n * 4 + t] = v;
        else adst_n[n * 4 + (t - 4)] = v;
    }
}

// ---------------- GEMM (layers 1-3): barrier-free, no LDS ----------------
// Both operands pre-swizzled fragment-major: per-lane coalesced 16B register loads,
// no __syncthreads -> compiler pipelines loads across iterations with vmcnt(N).
// 32x32x16 MFMA operand-swapped; L2 supertile 8m x 8n; M padded (no predicates).
__global__ __launch_bounds__(256) void mfma_gemm_kernel(const f16* __restrict__ Af,
                                                        const f16* __restrict__ Bf,
                                                        f16* __restrict__ C16) {
    int t = threadIdx.x;
    int wave = t >> 6, lane = t & 63;
    int gid = blockIdx.x;
    int g = gid >> 6, rblk = gid & 63;
    int nblk = rblk >> 3;
    int mblk = g * 8 + (rblk & 7);
    int rg0 = (wave >> 1) * 2;
    int cg0 = (wave & 1) * 2;

    floatx16 acc[2][2];
#pragma unroll
    for (int i = 0; i < 2; i++)
#pragma unroll
        for (int j = 0; j < 2; j++) acc[i][j] = (floatx16)(0.f);

    const f16* pa = Af + (size_t)mblk * 131072 + (size_t)lane * 8;
    const f16* pb = Bf + (size_t)nblk * 131072 + (size_t)lane * 8;

#pragma unroll 2
    for (int iter = 0; iter < 32; iter++) {
        size_t base = (size_t)iter * 4096;
        half8 afr[2][2], bfr[2][2];
#pragma unroll
        for (int kh = 0; kh < 2; kh++) {
#pragma unroll
            for (int i = 0; i < 2; i++) {
                afr[kh][i] = *(const half8*)&pa[base + kh * 2048 + (rg0 + i) * 512];
                bfr[kh][i] = *(const half8*)&pb[base + kh * 2048 + (cg0 + i) * 512];
            }
        }
#pragma unroll
        for (int kh = 0; kh < 2; kh++)
#pragma unroll
            for (int i = 0; i < 2; i++)
#pragma unroll
                for (int j = 0; j < 2; j++)
                    acc[i][j] = __builtin_amdgcn_mfma_f32_32x32x16_f16(bfr[kh][j], afr[kh][i],
                                                                       acc[i][j], 0, 0, 0);
    }

    int fr32 = lane & 31, kg = lane >> 5;
#pragma unroll
    for (int i = 0; i < 2; i++) {
        int row = mblk * 128 + rg0 * 32 + i * 32 + fr32;
#pragma unroll
        for (int j = 0; j < 2; j++) {
#pragma unroll
            for (int gq = 0; gq < 4; gq++) {
                f16x4 o;
#pragma unroll
                for (int r = 0; r < 4; r++) o[r] = (f16)acc[i][j][gq * 4 + r];
                *(f16x4*)&C16[(size_t)row * HC + nblk * 128 + cg0 * 32 + j * 32 + gq * 8 +
                              kg * 4] = o;
            }
        }
    }
}

// ---------------- fused attention + aggregation (block per node, chunk-4) ----------
// Concat layers write the next GEMM's A in fragment layout (af_off).
__global__ void agg_kernel(const f16* __restrict__ h16, const float* __restrict__ asrc,
                           const float* __restrict__ adst, const float* __restrict__ ae_self,
                           const int* __restrict__ ssrc, const float* __restrict__ pe,
                           const int* __restrict__ indptr, const float2* __restrict__ bnss,
                           const float* __restrict__ wsv, const float* __restrict__ wdv,
                           const float* __restrict__ bias3, const float* __restrict__ gw,
                           const float* __restrict__ gb, f16* __restrict__ out16,
                           float* __restrict__ asrc_n, float* __restrict__ adst_n,
                           float* __restrict__ out3, float* __restrict__ gate,
                           int layer, int concat) {
    __shared__ float buf[1024];
    __shared__ float red[32];
    int n = blockIdx.x, t = threadIdx.x;
    int h = t >> 6, lane = t & 63;
    int c4 = t * 4;

    float r = asrc[n * 4 + h] + adst[n * 4 + h] + ae_self[layer * 4 + h];
    r = (r > 0.f) ? r : 0.2f * r;
    float p = __expf(r);
    float denom = p;
    float ax, ay, az, aw;
    {
        f16x4 v = *(const f16x4*)&h16[(size_t)n * HC + c4];
        ax = p * (float)v[0]; ay = p * (float)v[1];
        az = p * (float)v[2]; aw = p * (float)v[3];
    }
    int s = indptr[n], epos = indptr[n + 1];
    for (int base = s; base < epos; base += 4) {
        int rem = epos - base;
        int src[4];
        float pv[4];
#pragma unroll
        for (int j = 0; j < 4; j++) {
            if (j < rem) {
                src[j] = ssrc[base + j];
                pv[j] = pe[(size_t)(base + j) * 4 + h];
            } else {
                src[j] = n;
                pv[j] = 0.f;
            }
        }
        f16x4 u[4];
#pragma unroll
        for (int j = 0; j < 4; j++) u[j] = *(const f16x4*)&h16[(size_t)src[j] * HC + c4];
#pragma unroll
        for (int j = 0; j < 4; j++) {
            denom += pv[j];
            ax += pv[j] * (float)u[j][0];
            ay += pv[j] * (float)u[j][1];
            az += pv[j] * (float)u[j][2];
            aw += pv[j] * (float)u[j][3];
        }
    }
    float inv = 1.0f / (denom + 1e-16f);
    ax *= inv; ay *= inv; az *= inv; aw *= inv;

    if (concat) {
        float vals[4] = {ax, ay, az, aw};
        f16x4 o;
        float sp[4] = {0.f, 0.f, 0.f, 0.f}, dp[4] = {0.f, 0.f, 0.f, 0.f};
#pragma unroll
        for (int k = 0; k < 4; k++) {
            int j = c4 + k;
            float2 ss = bnss[j];
            float val = fmaxf(fmaf(vals[k], ss.x, ss.y), 0.f);
            o[k] = (f16)val;
            float4 w4s = *(const float4*)&wsv[(size_t)j * 4];
            float4 w4d = *(const float4*)&wdv[(size_t)j * 4];
            sp[0] += val * w4s.x; sp[1] += val * w4s.y;
            sp[2] += val * w4s.z; sp[3] += val * w4s.w;
            dp[0] += val * w4d.x; dp[1] += val * w4d.y;
            dp[2] += val * w4d.z; dp[3] += val * w4d.w;
        }
        *(f16x4*)&out16[af_off(n, c4)] = o;
#pragma unroll
        for (int m = 1; m < 64; m <<= 1) {
#pragma unroll
            for (int j = 0; j < 4; j++) {
                sp[j] += __shfl_xor(sp[j], m);
                dp[j] += __shfl_xor(dp[j], m);
            }
        }
        if (lane == 0) {
#pragma unroll
            for (int j = 0; j < 4; j++) {
                red[h * 8 + j] = sp[j];
                red[h * 8 + 4 + j] = dp[j];
            }
        }
        __syncthreads();
        if (t < 8) {
            float v = red[t] + red[8 + t] + red[16 + t] + red[24 + t];
            if (t < 4) asrc_n[n * 4 + t] = v;
            else adst_n[n * 4 + (t - 4)] = v;
        }
    } else {
        buf[c4 + 0] = ax;
        buf[c4 + 1] = ay;
        buf[c4 + 2] = az;
        buf[c4 + 3] = aw;
        __syncthreads();
        if (t < 64) {
            float gpart = 0.f;
#pragma unroll
            for (int k = 0; k < 4; k++) {
                int c = t * 4 + k;
                float v2 = 0.25f * (buf[c] + buf[256 + c] + buf[512 + c] + buf[768 + c]) +
                           bias3[c];
                out3[(size_t)n * CC + c] = v2;
                gpart += v2 * gw[c];
            }
            for (int o = 32; o; o >>= 1) gpart += __shfl_down(gpart, o);
            if (t == 0) gate[n] = gpart + gb[0];
        }
    }
}

// ---------------- readout ----------------
__global__ void graphagg_kernel(const float* __restrict__ gate, const float* __restrict__ h3,
                                const int* __restrict__ bptr, float* __restrict__ graph) {
    __shared__ float red[256];
    __shared__ float wn[256];
    int b = blockIdx.x, t = threadIdx.x;
    int s = bptr[b], epos = bptr[b + 1];
    float m = -3.4e38f;
    for (int n = s + t; n < epos; n += 256) m = fmaxf(m, gate[n]);
    red[t] = m;
    __syncthreads();
    for (int o = 128; o; o >>= 1) {
        if (t < o) red[t] = fmaxf(red[t], red[t + o]);
        __syncthreads();
    }
    float mval = red[0];
    __syncthreads();
    float sum = 0.f;
    for (int n = s + t; n < epos; n += 256) sum += __expf(gate[n] - mval);
    red[t] = sum;
    __syncthreads();
    for (int o = 128; o; o >>= 1) {
        if (t < o) red[t] += red[t + o];
        __syncthreads();
    }
    float ssum = red[0];
    __syncthreads();
    float acc = 0.f;
    for (int base = s; base < epos; base += 256) {
        int n = base + t;
        wn[t] = (n < epos) ? __expf(gate[n] - mval) : 0.f;
        __syncthreads();
        int cnt = min(256, epos - base);
        for (int j = 0; j < cnt; j++) acc += wn[j] * h3[(size_t)(base + j) * CC + t];
        __syncthreads();
    }
    graph[b * CC + t] = acc / (ssum + 1e-16f);
}

__global__ void proj_kernel(const float* __restrict__ graph, const float* __restrict__ pw,
                            const float* __restrict__ pb, float* __restrict__ out) {
    __shared__ float g[256];
    int b = blockIdx.x, t = threadIdx.x;
    g[t] = graph[b * CC + t];
    __syncthreads();
    for (int j = t; j < 1024; j += 256) {
        float acc = pb[j];
        for (int c = 0; c < 256; c++) acc += g[c] * pw[c * 1024 + j];
        out[(size_t)b * 1024 + j] = acc;
    }
}

// ---------------- host ----------------
extern "C" void kernel_launch(void* const* d_in, const int* in_sizes, int n_in,
                              void* d_out, int out_size, void* d_ws, size_t ws_size,
                              hipStream_t stream) {
    const float* x = (const float*)d_in[0];
    const int* ei = (const int*)d_in[1];
    const float* ea = (const float*)d_in[2];
    const int* batch = (const int*)d_in[3];
    const float* w0 = (const float*)d_in[4];
    const float* w_rest = (const float*)d_in[5];
    const float* w_edge = (const float*)d_in[6];
    const float* att_src = (const float*)d_in[7];
    const float* att_dst = (const float*)d_in[8];
    const float* att_edge = (const float*)d_in[9];
    const float* bias012 = (const float*)d_in[10];
    const float* bias3 = (const float*)d_in[11];
    const float* bn_g = (const float*)d_in[12];
    const float* bn_b = (const float*)d_in[13];
    const float* bn_m = (const float*)d_in[14];
    const float* bn_v = (const float*)d_in[15];
    const float* gate_w = (const float*)d_in[16];
    const float* gate_b = (const float*)d_in[17];
    const float* proj_w = (const float*)d_in[18];
    const float* proj_b = (const float*)d_in[19];
    float* out = (float*)d_out;

    float* ws = (float*)d_ws;
    size_t off = 0;
    f16* h_lin = (f16*)(ws + off); off += (size_t)NP * HC / 2;   // GEMM output (row-major)
    f16* h_af = (f16*)(ws + off); off += (size_t)NP * HC / 2;    // GEMM input (Af layout)
    float* h3 = ws + off; off += (size_t)NN * CC;
    f16* wt = (f16*)(ws + off); off += (size_t)3 * HC * HC / 2;  // B^T fp16 (intermediate)
    f16* Bf = (f16*)(ws + off); off += (size_t)3 * HC * HC / 2;  // B fragment-major
    float* asrcA = ws + off; off += (size_t)NN * 4;
    float* adstA = ws + off; off += (size_t)NN * 4;
    float* asrcB = ws + off; off += (size_t)NN * 4;
    float* adstB = ws + off; off += (size_t)NN * 4;
    float* wsv = ws + off; off += (size_t)3 * HC * 4;
    float* wdv = ws + off; off += (size_t)3 * HC * 4;
    float* w0s = ws + off; off += 28;
    float* w0d = ws + off; off += 28;
    float2* bnss = (float2*)(ws + off); off += (size_t)3 * HC * 2;
    float* aeh_pk = ws + off; off += (size_t)EE * 16;
    float* pbuf = ws + off; off += (size_t)EE * 4;
    float* xagg = ws + off; off += (size_t)NN * 28;
    float* gate = ws + off; off += (size_t)NN;
    float* graph = ws + off; off += (size_t)BB * CC;
    float* ea_sums = ws + off; off += 4;
    float* Mmat = ws + off; off += 48;
    float* ae_self = ws + off; off += 16;
    int* counts = (int*)(ws + off); off += NN;
    int* partial = (int*)(ws + off); off += NN;
    int* psums = (int*)(ws + off); off += 128;
    int* indptr = (int*)(ws + off); off += NN + 1;
    int* fill = (int*)(ws + off); off += NN;
    int* sorted = (int*)(ws + off); off += EE;
    int* ssrc = (int*)(ws + off); off += EE;
    int* sdst = (int*)(ws + off); off += EE;
    int* bptr = (int*)(ws + off); off += BB + 1;

    hipMemsetAsync(ea_sums, 0, 4 * sizeof(float), stream);
    hipMemsetAsync(counts, 0, NN * sizeof(int), stream);
    hipMemsetAsync(fill, 0, NN * sizeof(int), stream);

    ea_sum_kernel<<<64, 256, 0, stream>>>(ea, ea_sums, EE);
    hist_kernel<<<(EE + 255) / 256, 256, 0, stream>>>(ei, counts, EE);
    int nblk = (NN + 255) / 256;  // 79
    scan1_kernel<<<nblk, 256, 0, stream>>>(counts, partial, psums, NN);
    scan2_kernel<<<1, 128, 0, stream>>>(psums, nblk);
    scan3_kernel<<<nblk, 256, 0, stream>>>(partial, psums, indptr, NN);
    scatter_kernel<<<(EE + 255) / 256, 256, 0, stream>>>(ei, indptr, fill, sorted, sdst, EE);
    bptr_kernel<<<(NN + 255) / 256, 256, 0, stream>>>(batch, bptr, NN, BB);
    wconv_kernel<<<dim3(16, 16, 3), 256, 0, stream>>>(w_rest, wt);
    bfrs_kernel<<<dim3(32, 8, 3), 256, 0, stream>>>(wt, Bf);
    mmat_all_kernel<<<4, 256, 0, stream>>>(w_edge, att_edge, ea_sums, Mmat, ae_self,
                                           1.0f / EE);
    pack_kernel<<<(EE + 255) / 256, 256, 0, stream>>>(ei, sorted, ea, Mmat, ssrc, aeh_pk);
    bnss_kernel<<<(3 * HC + 255) / 256, 256, 0, stream>>>(bias012, bn_g, bn_b, bn_m, bn_v,
                                                          bnss);
    wvec_kernel<<<dim3(1024, 3), 256, 0, stream>>>(w_rest, att_src, att_dst, wsv, wdv);
    w0vec_kernel<<<7, 256, 0, stream>>>(w0, att_src, att_dst, w0s, w0d);
    alpha0_kernel<<<(NN + 255) / 256, 256, 0, stream>>>(x, w0s, w0d, asrcA, adstA);

    // ---- layer 0 (commuted) ----
    edgep_kernel<<<(EE + 255) / 256, 256, 0, stream>>>(ssrc, sdst, aeh_pk, asrcA, adstA,
                                                       pbuf, 0);
    agg0x_kernel<<<(NN + 255) / 256, 256, 0, stream>>>(x, asrcA, adstA, ae_self, ssrc,
                                                       pbuf, indptr, xagg);
    gemm7f_kernel<<<NN, 256, 0, stream>>>(xagg, w0, bnss, wsv, wdv, h_af, asrcB, adstB);

    float* asrc_cur = asrcB;
    float* adst_cur = adstB;
    float* asrc_nxt = asrcA;
    float* adst_nxt = adstA;
    for (int i = 1; i < 4; i++) {
        mfma_gemm_kernel<<<(NP / 128) * (HC / 128), 256, 0, stream>>>(
            h_af, Bf + (size_t)(i - 1) * HC * HC, h_lin);
        edgep_kernel<<<(EE + 255) / 256, 256, 0, stream>>>(ssrc, sdst, aeh_pk, asrc_cur,
                                                           adst_cur, pbuf, i);
        agg_kernel<<<NN, 256, 0, stream>>>(
            h_lin, asrc_cur, adst_cur, ae_self, ssrc, pbuf, indptr, bnss + (size_t)i * HC,
            wsv + (size_t)i * HC * 4, wdv + (size_t)i * HC * 4, bias3, gate_w, gate_b,
            h_af, asrc_nxt, adst_nxt, h3, gate, i, (i < 3) ? 1 : 0);
        float* tmp = asrc_cur; asrc_cur = asrc_nxt; asrc_nxt = tmp;
        tmp = adst_cur; adst_cur = adst_nxt; adst_nxt = tmp;
    }

    graphagg_kernel<<<BB, 256, 0, stream>>>(gate, h3, bptr, graph);
    proj_kernel<<<BB, 256, 0, stream>>>(graph, proj_w, proj_b, out);
}